// Round 5
// baseline (191.671 us; speedup 1.0000x reference)
//
#include <hip/hip_runtime.h>
#include <hip/hip_bf16.h>
#include <math.h>

#define L 2048
#define D 1024
#define NH 16
#define HD 64
#define P 128
#define HDE 96                              /* extended head dim 80, padded to 96 */
#define CONTENT_SCALE 0.125f                /* 1/sqrt(64) */
#define PHASE_SCALE   0.35355339059327373f  /* 1/sqrt(8) */
#define KLS 104                             /* Kl LDS stride */
#define VT2 136                             /* Vt LDS stride (128 cols + pad) */
#define NSPLIT 2

typedef short bf16x8 __attribute__((ext_vector_type(8)));
typedef float f32x4 __attribute__((ext_vector_type(4)));
typedef float f32x16 __attribute__((ext_vector_type(16)));

__device__ inline ushort f2b(float x) {
    __hip_bfloat16 b = __float2bfloat16(x);
    return *(ushort*)&b;
}
__device__ inline float b2f(ushort u) {
    unsigned v = (unsigned)u << 16;
    union { unsigned u; float f; } c; c.u = v; return c.f;
}

// hardware sincos: v_sin/v_cos take REVOLUTIONS; reduce with fract
__device__ inline void sincos_hw(float ang, float* sn, float* cs) {
    float rev = ang * 0.15915494309189535f;
    rev -= floorf(rev);
    *sn = __builtin_amdgcn_sinf(rev);
    *cs = __builtin_amdgcn_cosf(rev);
}

// async global->LDS, 16B per lane; LDS dest = wave-uniform base + lane*16
__device__ inline void gld_lds16(const void* g, void* l) {
    __builtin_amdgcn_global_load_lds(
        (const __attribute__((address_space(1))) unsigned int*)g,
        (__attribute__((address_space(3))) unsigned int*)l,
        16, 0, 0);
}

// ---------------- fused prep: [0,4096) cvt fp32->bf16, [4096,8448) transpose W,
// [8448,8576) zero Qe/Ke pad cols 80..95
__global__ void prep_kernel(const float* __restrict__ xr, const float* __restrict__ xi,
                            ushort* __restrict__ xrb, ushort* __restrict__ xib,
                            const float* __restrict__ W0, const float* __restrict__ W1,
                            const float* __restrict__ W2, const float* __restrict__ W3,
                            const float* __restrict__ W4, const float* __restrict__ W5,
                            ushort* __restrict__ T0, ushort* __restrict__ T1,
                            ushort* __restrict__ T2, ushort* __restrict__ T3,
                            ushort* __restrict__ Tp,
                            ushort* __restrict__ Qe, ushort* __restrict__ Ke) {
    __shared__ float tile[32][33];
    const int b = blockIdx.x;
    const int tid = threadIdx.x;
    if (b < 4096) {                          // cvt: 2 tensors x 2048 blocks
        const float4* src = (b >> 11) ? (const float4*)xi : (const float4*)xr;
        ushort4* dst = (b >> 11) ? (ushort4*)xib : (ushort4*)xrb;
        int i = ((b & 2047) << 8) + tid;
        float4 v = src[i];
        ushort4 o;
        o.x = f2b(v.x); o.y = f2b(v.y); o.z = f2b(v.z); o.w = f2b(v.w);
        dst[i] = o;
    } else if (b < 8448) {                   // transpose+convert weights
        int w = b - 4096;
        const float* W; ushort* T; int ncols, n0, k0;
        if (w < 4096) {
            int z = w >> 10, t = w & 1023;
            n0 = (t & 31) * 32; k0 = (t >> 5) * 32; ncols = D;
            W = (z == 0) ? W0 : ((z == 1) ? W1 : ((z == 2) ? W2 : W3));
            T = (z == 0) ? T0 : ((z == 1) ? T1 : ((z == 2) ? T2 : T3));
        } else {
            int w2 = w - 4096;
            int z = w2 >> 7, t = w2 & 127;
            n0 = (t & 3) * 32; k0 = (t >> 2) * 32; ncols = P;
            W = z ? W5 : W4;
            T = Tp + (size_t)z * P * D;
        }
        int tx = tid & 31, ty = tid >> 5;
#pragma unroll
        for (int i = 0; i < 4; i++)
            tile[ty + i * 8][tx] = W[(size_t)(k0 + ty + i * 8) * ncols + n0 + tx];
        __syncthreads();
#pragma unroll
        for (int i = 0; i < 4; i++)
            T[(size_t)(n0 + ty + i * 8) * D + k0 + tx] = f2b(tile[tx][ty + i * 8]);
    } else {                                 // zpad
        int i = (b - 8448) * 256 + tid;      // 0 .. NH*L-1
        size_t base = (size_t)i * HDE + 80;
        uint4 z4 = make_uint4(0, 0, 0, 0);
        *(uint4*)(Qe + base) = z4;
        *(uint4*)(Qe + base + 8) = z4;
        *(uint4*)(Ke + base) = z4;
        *(uint4*)(Ke + base + 8) = z4;
    }
}

// ---------------- fused QKV + phase MFMA GEMM. z=0..2: Q/K/V; z=3: phase (x<2)
// STATIC double-buffered LDS (4 named arrays, x2-unrolled K loop).
__launch_bounds__(256)
__global__ void qkv_gemm(const ushort* __restrict__ Ab, const ushort* __restrict__ xib,
                         const ushort* __restrict__ Wtq, const ushort* __restrict__ Wtk,
                         const ushort* __restrict__ Wtv, const ushort* __restrict__ Wtp,
                         ushort* __restrict__ Qe, ushort* __restrict__ Ke,
                         ushort* __restrict__ Ve, const float* __restrict__ alpha,
                         const float* __restrict__ bqp, const float* __restrict__ bkp) {
    const int z = blockIdx.z;
    if (z == 3 && blockIdx.x >= 2) return;
    const ushort* At = (z == 3) ? xib : Ab;
    const ushort* Bt = (z == 0) ? Wtq : ((z == 1) ? Wtk : ((z == 2) ? Wtv : Wtp));
    __shared__ ushort As0[128 * 32], Bs0[128 * 32];
    __shared__ ushort As1[128 * 32], Bs1[128 * 32];
    const int tid = threadIdx.x;
    const int wave = tid >> 6, lane = tid & 63, quad = lane >> 4, ln16 = lane & 15;
    const int wm = wave >> 1, wn = wave & 1;
    const int m0 = blockIdx.y * 128, n0 = blockIdx.x * 128;
    f32x4 acc[4][4];
#pragma unroll
    for (int i = 0; i < 4; i++)
#pragma unroll
        for (int j = 0; j < 4; j++) acc[i][j] = (f32x4){0.f, 0.f, 0.f, 0.f};

    auto stage = [&](int kt, ushort* Asb, ushort* Bsb) {
#pragma unroll
        for (int i = 0; i < 2; i++) {
            int idx = i * 256 + tid;
            int r2 = idx >> 2, cc = idx & 3;
            gld_lds16(At + (size_t)(m0 + r2) * D + kt + cc * 8, &Asb[idx * 8]);
            gld_lds16(Bt + (size_t)(n0 + r2) * D + kt + cc * 8, &Bsb[idx * 8]);
        }
    };
    auto compute = [&](const ushort* Asb, const ushort* Bsb) {
        bf16x8 af[4], bfr[4];
#pragma unroll
        for (int t = 0; t < 4; t++) {
            af[t]  = *(const bf16x8*)(&Asb[(wm * 64 + t * 16 + ln16) * 32 + quad * 8]);
            bfr[t] = *(const bf16x8*)(&Bsb[(wn * 64 + t * 16 + ln16) * 32 + quad * 8]);
        }
#pragma unroll
        for (int i = 0; i < 4; i++)
#pragma unroll
            for (int j = 0; j < 4; j++)
                acc[i][j] = __builtin_amdgcn_mfma_f32_16x16x32_bf16(af[i], bfr[j], acc[i][j], 0, 0, 0);
    };

    stage(0, As0, Bs0);
    __syncthreads();
    for (int kt = 0; kt < D; kt += 64) {
        stage(kt + 32, As1, Bs1);            // write b1 (readers done at prev barrier)
        compute(As0, Bs0);                   // read b0 (no alias with b1 writes)
        __syncthreads();
        if (kt + 64 < D) stage(kt + 64, As0, Bs0);
        compute(As1, Bs1);
        __syncthreads();
    }

    if (z == 2) {                            // V epilogue -> transposed Vte[h][d][L]
        int hn = (n0 + wn * 64) >> 6;
#pragma unroll
        for (int i = 0; i < 4; i++)
#pragma unroll
            for (int j = 0; j < 4; j++) {
                int d = j * 16 + ln16;
                int m = m0 + wm * 64 + i * 16 + quad * 4;
                ushort4 pk;
                pk.x = f2b(acc[i][j][0]); pk.y = f2b(acc[i][j][1]);
                pk.z = f2b(acc[i][j][2]); pk.w = f2b(acc[i][j][3]);
                *(ushort4*)(Ve + ((size_t)hn * HD + d) * L + m) = pk;
            }
    } else if (z < 2) {                      // Q/K epilogue, row-major [h][m][c]
        int hn = (n0 + wn * 64) >> 6;
        float s = (z == 0) ? (1.f - 1.f / (1.f + __expf(-alpha[hn]))) * CONTENT_SCALE : 1.f;
        ushort* dst = (z == 0) ? Qe : Ke;
#pragma unroll
        for (int i = 0; i < 4; i++)
#pragma unroll
            for (int j = 0; j < 4; j++) {
                int dcol = j * 16 + ln16;
#pragma unroll
                for (int r = 0; r < 4; r++) {
                    int m = m0 + wm * 64 + i * 16 + quad * 4 + r;
                    dst[((size_t)hn * L + m) * HDE + dcol] = f2b(acc[i][j][r] * s);
                }
            }
    } else {                                 // phase epilogue -> Qe/Ke cols 64..79
#pragma unroll
        for (int j = 0; j < 4; j++) {
            int cg = n0 + wn * 64 + j * 16 + ln16;   // 0..255
            int isQ = cg < P;
            int c = cg & (P - 1);
            int hh = c >> 3, jj = c & 7;
            float b = isQ ? bqp[c] : bkp[c];
            float sc = isQ ? (1.f / (1.f + __expf(-alpha[hh]))) * PHASE_SCALE : 1.f;
            float invf = __expf(-((float)(c & ~1) / 128.f) * 9.210340371976184f);
            ushort* dst = isQ ? Qe : Ke;
#pragma unroll
            for (int i = 0; i < 4; i++)
#pragma unroll
                for (int r = 0; r < 4; r++) {
                    int m = m0 + wm * 64 + i * 16 + quad * 4 + r;
                    float qt = acc[i][j][r] + b + (float)m * invf;
                    float sn, cs;
                    sincos_hw(qt, &sn, &cs);
                    size_t base = ((size_t)hh * L + m) * HDE;
                    dst[base + 64 + jj] = f2b(sc * cs);
                    dst[base + 72 + jj] = f2b(sc * sn);
                }
        }
    }
}

// ---------------- flash attention: 32x32x16 MFMA, swapped QK^T (P lane-local),
// KVBLK=128, l-sum via MFMA with ones-B, NSPLIT=2 CU-pairing.
__launch_bounds__(256, 2)
__global__ void flash_attn(const ushort* __restrict__ Qe, const ushort* __restrict__ Ke,
                           const ushort* __restrict__ Vte,
                           ushort* __restrict__ Opart, float* __restrict__ ml) {
    const int b = blockIdx.x;
    const int xcd = b & 7;
    const int r = b >> 3;                    // 0..63 per XCD
    const int idx = r & 31, sub = r >> 5;    // r and r+32 land on the same CU
    const int hbit = idx >> 4, c0i = idx & 15;
    const int c = sub ? 15 - c0i : c0i;      // complementary chunk sizes pair up
    const int z = sub;
    const int h = xcd * 2 + hbit;
    const int tid = threadIdx.x;
    const int wave = tid >> 6, lane = tid & 63;
    const int ln32 = lane & 31, hf = lane >> 5;

    const int nT = c + 1;                    // 64-key tiles [z*(c+1), (z+1)*(c+1))
    const int s0 = z * nT;
    const int nR = (nT + 1) >> 1;            // 128-key rounds
    const int qw = c * 128 + wave * 32;      // wave's 32-row q strip

    __shared__ ushort Kl[128 * KLS];         // 26.6 KB
    __shared__ ushort Vt[64 * VT2];          // 17.4 KB

    const ushort* Kh = Ke + (size_t)h * L * HDE;
    const ushort* Vh = Vte + (size_t)h * HD * L;
    const ushort* Qh = Qe + (size_t)h * L * HDE;
    ushort* Op = Opart + (size_t)z * L * D;
    float* mlp = ml + (size_t)z * NH * L + (size_t)h * L;

    bf16x8 onesv;
#pragma unroll
    for (int i = 0; i < 8; i++) onesv[i] = (short)0x3F80;   // bf16 1.0

    // Q B-frags (col=q=ln32, contract c = cc*16 + hf*8 + j), loaded once
    bf16x8 qa[6];
#pragma unroll
    for (int cc = 0; cc < 6; cc++)
        qa[cc] = *(const bf16x8*)(Qh + (size_t)(qw + ln32) * HDE + cc * 16 + hf * 8);

    f32x16 o[2], olv;
#pragma unroll
    for (int i = 0; i < 16; i++) { o[0][i] = 0.f; o[1][i] = 0.f; olv[i] = 0.f; }

    // staging geometry (constant per thread)
    int rowk[6], colk[6];
#pragma unroll
    for (int ii = 0; ii < 6; ii++) {
        int ix = ii * 256 + tid;             // 1536 = 128 rows x 12 16B-chunks
        rowk[ii] = ix / 12; colk[ii] = ix - rowk[ii] * 12;
    }
    int dv[4], cv[4];
#pragma unroll
    for (int ii = 0; ii < 4; ii++) {
        int ix = ii * 256 + tid;             // 1024 = 64 d-rows x 16 16B-chunks
        dv[ii] = ix >> 4; cv[ii] = ix & 15;
    }

    bf16x8 kreg[6], vreg[4];
    {
        int kk = s0 * 64;
#pragma unroll
        for (int ii = 0; ii < 6; ii++)
            kreg[ii] = *(const bf16x8*)(Kh + (size_t)(kk + rowk[ii]) * HDE + colk[ii] * 8);
#pragma unroll
        for (int ii = 0; ii < 4; ii++)
            vreg[ii] = *(const bf16x8*)(Vh + (size_t)dv[ii] * L + kk + cv[ii] * 8);
    }

    for (int rr = 0; rr < nR; rr++) {
        const int tk0 = (s0 + rr * 2) * 64;
        __syncthreads();
#pragma unroll
        for (int ii = 0; ii < 6; ii++)
            *(bf16x8*)(&Kl[rowk[ii] * KLS + colk[ii] * 8]) = kreg[ii];
#pragma unroll
        for (int ii = 0; ii < 4; ii++)
            *(bf16x8*)(&Vt[dv[ii] * VT2 + cv[ii] * 8]) = vreg[ii];
        __syncthreads();

        if (rr + 1 < nR) {                   // prefetch next 128-key round
            int kk = tk0 + 128;
#pragma unroll
            for (int ii = 0; ii < 6; ii++)
                kreg[ii] = *(const bf16x8*)(Kh + (size_t)(kk + rowk[ii]) * HDE + colk[ii] * 8);
#pragma unroll
            for (int ii = 0; ii < 4; ii++)
                vreg[ii] = *(const bf16x8*)(Vh + (size_t)dv[ii] * L + kk + cv[ii] * 8);
        }

#pragma unroll
        for (int hb = 0; hb < 2; hb++) {
            const int tt = rr * 2 + hb;
            const int k0 = tk0 + hb * 64;
            if (tt < nT && k0 < qw + 32) {   // wave-uniform skip
                // QK^T swapped: s2[kb] = K_tile(32k x 96c) . Q^T -> D[k][q], col=q=ln32
                f32x16 s2[2];
#pragma unroll
                for (int i = 0; i < 16; i++) { s2[0][i] = 0.f; s2[1][i] = 0.f; }
                __builtin_amdgcn_s_setprio(1);
#pragma unroll
                for (int kb = 0; kb < 2; kb++)
#pragma unroll
                    for (int cc = 0; cc < 6; cc++) {
                        bf16x8 kf = *(const bf16x8*)(&Kl[(hb * 64 + kb * 32 + ln32) * KLS + cc * 16 + hf * 8]);
                        s2[kb] = __builtin_amdgcn_mfma_f32_32x32x16_bf16(kf, qa[cc], s2[kb], 0, 0, 0);
                    }
                __builtin_amdgcn_s_setprio(0);

                if (k0 + 63 > qw) {          // diagonal region: causal mask
#pragma unroll
                    for (int kb = 0; kb < 2; kb++)
#pragma unroll
                        for (int rg = 0; rg < 16; rg++) {
                            int key = k0 + kb * 32 + (rg & 3) + 8 * (rg >> 2) + 4 * hf;
                            if (key > qw + ln32) s2[kb][rg] = -1e30f;
                        }
                }

                // P = exp(s) in place (scores bounded; no max, no rescale)
#pragma unroll
                for (int kb = 0; kb < 2; kb++)
#pragma unroll
                    for (int rg = 0; rg < 16; rg++)
                        s2[kb][rg] = __expf(s2[kb][rg]);

                // pack P->bf16 pairs (per t-quad: X = regs 4t,4t+1; Y = 4t+2,4t+3)
                unsigned Xp[2][4], Yp[2][4];
#pragma unroll
                for (int kb = 0; kb < 2; kb++)
#pragma unroll
                    for (int tq = 0; tq < 4; tq++) {
                        asm("v_cvt_pk_bf16_f32 %0, %1, %2"
                            : "=v"(Xp[kb][tq]) : "v"(s2[kb][4 * tq + 0]), "v"(s2[kb][4 * tq + 1]));
                        asm("v_cvt_pk_bf16_f32 %0, %1, %2"
                            : "=v"(Yp[kb][tq]) : "v"(s2[kb][4 * tq + 2]), "v"(s2[kb][4 * tq + 3]));
                    }

                // build PV A-frags via half-exchange: pa[m] covers k = m*16 + hf*8 + j
                bf16x8 pa[4];
#pragma unroll
                for (int m = 0; m < 4; m++) {
                    int kb = m >> 1, te = 2 * (m & 1), to = te + 1;
                    unsigned x0 = Xp[kb][te], x1 = Xp[kb][to];
                    unsigned y0 = Yp[kb][te], y1 = Yp[kb][to];
                    asm("v_permlane32_swap_b32 %0, %1" : "+v"(x0), "+v"(x1));
                    asm("v_permlane32_swap_b32 %0, %1" : "+v"(y0), "+v"(y1));
                    union { unsigned u[4]; bf16x8 v; } pb;
                    pb.u[0] = x0; pb.u[1] = y0; pb.u[2] = x1; pb.u[3] = y1;
                    pa[m] = pb.v;
                }

                // PV: o[db] (rows q, cols d = db*32+ln32); l-sum via ones-B MFMA
                __builtin_amdgcn_s_setprio(1);
#pragma unroll
                for (int m = 0; m < 4; m++) {
#pragma unroll
                    for (int db = 0; db < 2; db++) {
                        bf16x8 vf = *(const bf16x8*)(&Vt[(db * 32 + ln32) * VT2 + hb * 64 + m * 16 + hf * 8]);
                        o[db] = __builtin_amdgcn_mfma_f32_32x32x16_bf16(pa[m], vf, o[db], 0, 0, 0);
                    }
                    olv = __builtin_amdgcn_mfma_f32_32x32x16_bf16(pa[m], onesv, olv, 0, 0, 0);
                }
                __builtin_amdgcn_s_setprio(0);
            }
        }
    }

    // l write: olv row q = (rg&3)+8*(rg>>2)+4*hf, all cols equal -> col 0 writes
    if (ln32 == 0) {
#pragma unroll
        for (int rg = 0; rg < 16; rg++) {
            int q = qw + (rg & 3) + 8 * (rg >> 2) + 4 * hf;
            mlp[q] = olv[rg];
        }
    }
    // write partial O: lane col d = db*32+ln32, row q = (rg&3)+8*(rg>>2)+4*hf
#pragma unroll
    for (int db = 0; db < 2; db++)
#pragma unroll
        for (int rg = 0; rg < 16; rg++) {
            int q = qw + (rg & 3) + 8 * (rg >> 2) + 4 * hf;
            Op[(size_t)q * D + h * HD + db * 32 + ln32] = f2b(o[db][rg]);
        }
}

// ---------------- Wo GEMM with FUSED split-combine: A = (Op0+Op1)*1/(l0+l1)
// (bit-identical to old comb->AOb->wo path: same fp32 sum, same f2b rounding).
// 128x64 output tiles -> grid 16x16 = 256 blocks (one per CU; old 128 used half
// the machine). A reg-staged (combine needs VALU), B via gld_lds16 direct.
__launch_bounds__(256)
__global__ void wo_gemm(const ushort* __restrict__ Opart, const float* __restrict__ ml,
                        const ushort* __restrict__ Bt, float* __restrict__ C) {
    __shared__ ushort As[128 * 32];          // 8 KB
    __shared__ ushort Bs[64 * 32];           // 4 KB
    __shared__ float linv[128 * 16];         // 8 KB: 1/(l0+l1) per (row, head)
    const int tid = threadIdx.x;
    const int wave = tid >> 6, lane = tid & 63, quad = lane >> 4, ln16 = lane & 15;
    const int m0 = blockIdx.y * 128, n0 = blockIdx.x * 64;
    const size_t LD = (size_t)L * D;

    // per-block normalizers: linv[r][h] = 1/(ml[0][h][m0+r] + ml[1][h][m0+r])
#pragma unroll
    for (int i = 0; i < 8; i++) {
        int ix = i * 256 + tid;              // 2048 = 128 rows x 16 heads
        int rr = ix >> 4, hh = ix & 15;
        float l0 = ml[(size_t)hh * L + m0 + rr];
        float l1 = ml[(size_t)NH * L + (size_t)hh * L + m0 + rr];
        linv[ix] = 1.f / (l0 + l1);
    }

    // staging geometry
    const int arow = tid >> 1, ac = (tid & 1) * 16;   // A: 16 elems/thread (32B)
    const int brow = tid >> 2, bc8 = tid & 3;         // B: 8 elems/thread (16B)

    f32x4 acc[2][4];
#pragma unroll
    for (int i = 0; i < 2; i++)
#pragma unroll
        for (int j = 0; j < 4; j++) acc[i][j] = (f32x4){0.f, 0.f, 0.f, 0.f};

    bf16x8 a0v0, a0v1, a1v0, a1v1;
    {   // preload kt=0 A fragments
        const ushort* a0 = Opart + (size_t)(m0 + arow) * D + ac;
        a0v0 = *(const bf16x8*)(a0);      a0v1 = *(const bf16x8*)(a0 + 8);
        a1v0 = *(const bf16x8*)(a0 + LD); a1v1 = *(const bf16x8*)(a0 + LD + 8);
    }

    for (int kt = 0; kt < D; kt += 32) {
        __syncthreads();                     // readers of prev tile done (and linv ready)
        {   // combine + write A tile
            float iv = linv[arow * 16 + ((kt + ac) >> 6)];
            bf16x8 w0, w1;
#pragma unroll
            for (int j = 0; j < 8; j++) {
                w0[j] = (short)f2b((b2f((ushort)a0v0[j]) + b2f((ushort)a1v0[j])) * iv);
                w1[j] = (short)f2b((b2f((ushort)a0v1[j]) + b2f((ushort)a1v1[j])) * iv);
            }
            *(bf16x8*)(&As[arow * 32 + ac]) = w0;
            *(bf16x8*)(&As[arow * 32 + ac + 8]) = w1;
        }
        gld_lds16(Bt + (size_t)(n0 + brow) * D + kt + bc8 * 8, &Bs[tid * 8]);
        __syncthreads();                     // drains gld_lds + ds_writes

        if (kt + 32 < D) {                   // prefetch next A (overlaps compute)
            const ushort* a0 = Opart + (size_t)(m0 + arow) * D + kt + 32 + ac;
            a0v0 = *(const bf16x8*)(a0);      a0v1 = *(const bf16x8*)(a0 + 8);
            a1v0 = *(const bf16x8*)(a0 + LD); a1v1 = *(const bf16x8*)(a0 + LD + 8);
        }

        bf16x8 af[2], bfr[4];
#pragma unroll
        for (int i = 0; i < 2; i++)
            af[i] = *(const bf16x8*)(&As[(wave * 32 + i * 16 + ln16) * 32 + quad * 8]);
#pragma unroll
        for (int j = 0; j < 4; j++)
            bfr[j] = *(const bf16x8*)(&Bs[(j * 16 + ln16) * 32 + quad * 8]);
#pragma unroll
        for (int i = 0; i < 2; i++)
#pragma unroll
            for (int j = 0; j < 4; j++)
                acc[i][j] = __builtin_amdgcn_mfma_f32_16x16x32_bf16(af[i], bfr[j], acc[i][j], 0, 0, 0);
    }
#pragma unroll
    for (int i = 0; i < 2; i++)
#pragma unroll
        for (int j = 0; j < 4; j++)
#pragma unroll
            for (int r = 0; r < 4; r++) {
                int m = m0 + wave * 32 + i * 16 + quad * 4 + r;
                int n = n0 + j * 16 + ln16;
                C[(size_t)m * D + n] = acc[i][j][r];
            }
}

// ---------------- residual + LayerNorm (wave-shuffle reduce) + x_imag copy
__global__ void ln_kernel(const float* __restrict__ xr, const float* __restrict__ o2,
                          const float* __restrict__ gamma, const float* __restrict__ beta,
                          float* __restrict__ outp, const float4* __restrict__ xi4,
                          float4* __restrict__ out1) {
    int l = blockIdx.x;
    int tid = threadIdx.x;
    int wave = tid >> 6;
    __shared__ float red[8];
    float hv[4];
    float s = 0.f;
#pragma unroll
    for (int i = 0; i < 4; i++) {
        int c = tid + i * 256;
        hv[i] = xr[(size_t)l * D + c] + o2[(size_t)l * D + c];
        s += hv[i];
    }
    out1[(size_t)l * (D / 4) + tid] = xi4[(size_t)l * (D / 4) + tid];
#pragma unroll
    for (int off = 1; off < 64; off <<= 1) s += __shfl_xor(s, off);
    if ((tid & 63) == 0) red[wave] = s;
    __syncthreads();
    float mu = (red[0] + red[1] + red[2] + red[3]) * (1.f / D);
    float v = 0.f;
#pragma unroll
    for (int i = 0; i < 4; i++) { float d = hv[i] - mu; v += d * d; }
#pragma unroll
    for (int off = 1; off < 64; off <<= 1) v += __shfl_xor(v, off);
    __syncthreads();
    if ((tid & 63) == 0) red[4 + wave] = v;
    __syncthreads();
    float rstd = rsqrtf((red[4] + red[5] + red[6] + red[7]) * (1.f / D) + 1e-5f);
#pragma unroll
    for (int i = 0; i < 4; i++) {
        int c = tid + i * 256;
        outp[(size_t)l * D + c] = (hv[i] - mu) * rstd * gamma[c] + beta[c];
    }
}

extern "C" void kernel_launch(void* const* d_in, const int* in_sizes, int n_in,
                              void* d_out, int out_size, void* d_ws, size_t ws_size,
                              hipStream_t stream) {
    const float* xr    = (const float*)d_in[0];
    const float* xi    = (const float*)d_in[1];
    const float* Wq    = (const float*)d_in[2];
    const float* Wk    = (const float*)d_in[3];
    const float* Wv    = (const float*)d_in[4];
    const float* Wqp   = (const float*)d_in[5];
    const float* bqp   = (const float*)d_in[6];
    const float* Wkp   = (const float*)d_in[7];
    const float* bkp   = (const float*)d_in[8];
    const float* Wo    = (const float*)d_in[9];
    const float* alpha = (const float*)d_in[10];
    const float* gamma = (const float*)d_in[11];
    const float* beta  = (const float*)d_in[12];

    const size_t LD = (size_t)L * D;
    const size_t MB = 1024 * 1024;

    // d_out A [0,8MB): xib(4, dead after qkv z=3) | Wot(2) | Wtq(2)
    //                  -> LN fp32 output (last)
    // d_out B [8,16MB): xrb(4) | Wtk(2) | Wtv(2) -> x_imag copy (last, via ln)
    char* A8 = (char*)d_out;
    char* B8 = A8 + LD * 4;
    ushort* xib = (ushort*)A8;
    ushort* Wot = (ushort*)(A8 + 4 * MB);
    ushort* Wtq = (ushort*)(A8 + 6 * MB);
    ushort* xrb = (ushort*)B8;
    ushort* Wtk = (ushort*)(B8 + 4 * MB);
    ushort* Wtv = (ushort*)(B8 + 6 * MB);
    float* outf = (float*)d_out;

    // ws: Qe(6.29) | Ke(6.29) | Vte(4.19, transposed [h][d][L]) | Wqpkt(0.52)
    //     | Opart(8) | ml(0.26).  O2 fp32 overlays ws[0,8MB) (Qe/Ke dead after flash).
    ushort* Qe = (ushort*)d_ws;
    ushort* Ke = Qe + (size_t)NH * L * HDE;
    ushort* Ve = Ke + (size_t)NH * L * HDE;
    ushort* Wqpkt = Ve + (size_t)NH * L * HD;
    ushort* Opart = Wqpkt + (size_t)256 * D;            // NSPLIT x L*D bf16 = 8 MB
    float*  mlbuf = (float*)(Opart + (size_t)NSPLIT * LD);
    float*  O2 = (float*)d_ws;

    prep_kernel<<<8576, 256, 0, stream>>>(xr, xi, xrb, xib,
                                          Wq, Wk, Wv, Wo, Wqp, Wkp,
                                          Wtq, Wtk, Wtv, Wot, Wqpkt, Qe, Ke);

    qkv_gemm<<<dim3(8, 16, 4), 256, 0, stream>>>(xrb, xib, Wtq, Wtk, Wtv, Wqpkt,
                                                 Qe, Ke, Ve, alpha, bqp, bkp);

    flash_attn<<<512, 256, 0, stream>>>(Qe, Ke, Ve, Opart, mlbuf);

    wo_gemm<<<dim3(16, 16), 256, 0, stream>>>(Opart, mlbuf, Wot, O2);

    ln_kernel<<<L, 256, 0, stream>>>(xr, O2, gamma, beta, outf,
                                     (const float4*)xi, (float4*)(B8));
}

// Round 6
// 180.471 us; speedup vs baseline: 1.0621x; 1.0621x over previous
//
#include <hip/hip_runtime.h>
#include <hip/hip_bf16.h>
#include <math.h>

#define L 2048
#define D 1024
#define NH 16
#define HD 64
#define P 128
#define HDE 96                              /* extended head dim 80, padded to 96 */
#define CONTENT_SCALE 0.125f                /* 1/sqrt(64) */
#define PHASE_SCALE   0.35355339059327373f  /* 1/sqrt(8) */
#define KLS 104                             /* Kl LDS stride */
#define VT2 136                             /* Vt LDS stride (128 cols + pad) */
#define NSPLIT 2

typedef short bf16x8 __attribute__((ext_vector_type(8)));
typedef float f32x4 __attribute__((ext_vector_type(4)));
typedef float f32x16 __attribute__((ext_vector_type(16)));

__device__ inline ushort f2b(float x) {
    __hip_bfloat16 b = __float2bfloat16(x);
    return *(ushort*)&b;
}
__device__ inline float b2f(ushort u) {
    unsigned v = (unsigned)u << 16;
    union { unsigned u; float f; } c; c.u = v; return c.f;
}

// hardware sincos: v_sin/v_cos take REVOLUTIONS; reduce with fract
__device__ inline void sincos_hw(float ang, float* sn, float* cs) {
    float rev = ang * 0.15915494309189535f;
    rev -= floorf(rev);
    *sn = __builtin_amdgcn_sinf(rev);
    *cs = __builtin_amdgcn_cosf(rev);
}

// async global->LDS, 16B per lane; LDS dest = wave-uniform base + lane*16
__device__ inline void gld_lds16(const void* g, void* l) {
    __builtin_amdgcn_global_load_lds(
        (const __attribute__((address_space(1))) unsigned int*)g,
        (__attribute__((address_space(3))) unsigned int*)l,
        16, 0, 0);
}

// ---------------- fused prep: [0,4096) cvt fp32->bf16, [4096,8448) transpose W,
// [8448,8576) zero Qe/Ke pad cols 80..95
__global__ void prep_kernel(const float* __restrict__ xr, const float* __restrict__ xi,
                            ushort* __restrict__ xrb, ushort* __restrict__ xib,
                            const float* __restrict__ W0, const float* __restrict__ W1,
                            const float* __restrict__ W2, const float* __restrict__ W3,
                            const float* __restrict__ W4, const float* __restrict__ W5,
                            ushort* __restrict__ T0, ushort* __restrict__ T1,
                            ushort* __restrict__ T2, ushort* __restrict__ T3,
                            ushort* __restrict__ Tp,
                            ushort* __restrict__ Qe, ushort* __restrict__ Ke) {
    __shared__ float tile[32][33];
    const int b = blockIdx.x;
    const int tid = threadIdx.x;
    if (b < 4096) {                          // cvt: 2 tensors x 2048 blocks
        const float4* src = (b >> 11) ? (const float4*)xi : (const float4*)xr;
        ushort4* dst = (b >> 11) ? (ushort4*)xib : (ushort4*)xrb;
        int i = ((b & 2047) << 8) + tid;
        float4 v = src[i];
        ushort4 o;
        o.x = f2b(v.x); o.y = f2b(v.y); o.z = f2b(v.z); o.w = f2b(v.w);
        dst[i] = o;
    } else if (b < 8448) {                   // transpose+convert weights
        int w = b - 4096;
        const float* W; ushort* T; int ncols, n0, k0;
        if (w < 4096) {
            int z = w >> 10, t = w & 1023;
            n0 = (t & 31) * 32; k0 = (t >> 5) * 32; ncols = D;
            W = (z == 0) ? W0 : ((z == 1) ? W1 : ((z == 2) ? W2 : W3));
            T = (z == 0) ? T0 : ((z == 1) ? T1 : ((z == 2) ? T2 : T3));
        } else {
            int w2 = w - 4096;
            int z = w2 >> 7, t = w2 & 127;
            n0 = (t & 3) * 32; k0 = (t >> 2) * 32; ncols = P;
            W = z ? W5 : W4;
            T = Tp + (size_t)z * P * D;
        }
        int tx = tid & 31, ty = tid >> 5;
#pragma unroll
        for (int i = 0; i < 4; i++)
            tile[ty + i * 8][tx] = W[(size_t)(k0 + ty + i * 8) * ncols + n0 + tx];
        __syncthreads();
#pragma unroll
        for (int i = 0; i < 4; i++)
            T[(size_t)(n0 + ty + i * 8) * D + k0 + tx] = f2b(tile[tx][ty + i * 8]);
    } else {                                 // zpad
        int i = (b - 8448) * 256 + tid;      // 0 .. NH*L-1
        size_t base = (size_t)i * HDE + 80;
        uint4 z4 = make_uint4(0, 0, 0, 0);
        *(uint4*)(Qe + base) = z4;
        *(uint4*)(Qe + base + 8) = z4;
        *(uint4*)(Ke + base) = z4;
        *(uint4*)(Ke + base + 8) = z4;
    }
}

// ---------------- fused QKV + phase MFMA GEMM. z=0..2: Q/K/V; z=3: phase (x<2)
// STATIC double-buffered LDS (4 named arrays, x2-unrolled K loop).
__launch_bounds__(256)
__global__ void qkv_gemm(const ushort* __restrict__ Ab, const ushort* __restrict__ xib,
                         const ushort* __restrict__ Wtq, const ushort* __restrict__ Wtk,
                         const ushort* __restrict__ Wtv, const ushort* __restrict__ Wtp,
                         ushort* __restrict__ Qe, ushort* __restrict__ Ke,
                         ushort* __restrict__ Ve, const float* __restrict__ alpha,
                         const float* __restrict__ bqp, const float* __restrict__ bkp) {
    const int z = blockIdx.z;
    if (z == 3 && blockIdx.x >= 2) return;
    const ushort* At = (z == 3) ? xib : Ab;
    const ushort* Bt = (z == 0) ? Wtq : ((z == 1) ? Wtk : ((z == 2) ? Wtv : Wtp));
    __shared__ ushort As0[128 * 32], Bs0[128 * 32];
    __shared__ ushort As1[128 * 32], Bs1[128 * 32];
    const int tid = threadIdx.x;
    const int wave = tid >> 6, lane = tid & 63, quad = lane >> 4, ln16 = lane & 15;
    const int wm = wave >> 1, wn = wave & 1;
    const int m0 = blockIdx.y * 128, n0 = blockIdx.x * 128;
    f32x4 acc[4][4];
#pragma unroll
    for (int i = 0; i < 4; i++)
#pragma unroll
        for (int j = 0; j < 4; j++) acc[i][j] = (f32x4){0.f, 0.f, 0.f, 0.f};

    auto stage = [&](int kt, ushort* Asb, ushort* Bsb) {
#pragma unroll
        for (int i = 0; i < 2; i++) {
            int idx = i * 256 + tid;
            int r2 = idx >> 2, cc = idx & 3;
            gld_lds16(At + (size_t)(m0 + r2) * D + kt + cc * 8, &Asb[idx * 8]);
            gld_lds16(Bt + (size_t)(n0 + r2) * D + kt + cc * 8, &Bsb[idx * 8]);
        }
    };
    auto compute = [&](const ushort* Asb, const ushort* Bsb) {
        bf16x8 af[4], bfr[4];
#pragma unroll
        for (int t = 0; t < 4; t++) {
            af[t]  = *(const bf16x8*)(&Asb[(wm * 64 + t * 16 + ln16) * 32 + quad * 8]);
            bfr[t] = *(const bf16x8*)(&Bsb[(wn * 64 + t * 16 + ln16) * 32 + quad * 8]);
        }
#pragma unroll
        for (int i = 0; i < 4; i++)
#pragma unroll
            for (int j = 0; j < 4; j++)
                acc[i][j] = __builtin_amdgcn_mfma_f32_16x16x32_bf16(af[i], bfr[j], acc[i][j], 0, 0, 0);
    };

    stage(0, As0, Bs0);
    __syncthreads();
    for (int kt = 0; kt < D; kt += 64) {
        stage(kt + 32, As1, Bs1);            // write b1 (readers done at prev barrier)
        compute(As0, Bs0);                   // read b0 (no alias with b1 writes)
        __syncthreads();
        if (kt + 64 < D) stage(kt + 64, As0, Bs0);
        compute(As1, Bs1);
        __syncthreads();
    }

    if (z == 2) {                            // V epilogue -> transposed Vte[h][d][L]
        int hn = (n0 + wn * 64) >> 6;
#pragma unroll
        for (int i = 0; i < 4; i++)
#pragma unroll
            for (int j = 0; j < 4; j++) {
                int d = j * 16 + ln16;
                int m = m0 + wm * 64 + i * 16 + quad * 4;
                ushort4 pk;
                pk.x = f2b(acc[i][j][0]); pk.y = f2b(acc[i][j][1]);
                pk.z = f2b(acc[i][j][2]); pk.w = f2b(acc[i][j][3]);
                *(ushort4*)(Ve + ((size_t)hn * HD + d) * L + m) = pk;
            }
    } else if (z < 2) {                      // Q/K epilogue, row-major [h][m][c]
        int hn = (n0 + wn * 64) >> 6;
        float s = (z == 0) ? (1.f - 1.f / (1.f + __expf(-alpha[hn]))) * CONTENT_SCALE : 1.f;
        ushort* dst = (z == 0) ? Qe : Ke;
#pragma unroll
        for (int i = 0; i < 4; i++)
#pragma unroll
            for (int j = 0; j < 4; j++) {
                int dcol = j * 16 + ln16;
#pragma unroll
                for (int r = 0; r < 4; r++) {
                    int m = m0 + wm * 64 + i * 16 + quad * 4 + r;
                    dst[((size_t)hn * L + m) * HDE + dcol] = f2b(acc[i][j][r] * s);
                }
            }
    } else {                                 // phase epilogue -> Qe/Ke cols 64..79
#pragma unroll
        for (int j = 0; j < 4; j++) {
            int cg = n0 + wn * 64 + j * 16 + ln16;   // 0..255
            int isQ = cg < P;
            int c = cg & (P - 1);
            int hh = c >> 3, jj = c & 7;
            float b = isQ ? bqp[c] : bkp[c];
            float sc = isQ ? (1.f / (1.f + __expf(-alpha[hh]))) * PHASE_SCALE : 1.f;
            float invf = __expf(-((float)(c & ~1) / 128.f) * 9.210340371976184f);
            ushort* dst = isQ ? Qe : Ke;
#pragma unroll
            for (int i = 0; i < 4; i++)
#pragma unroll
                for (int r = 0; r < 4; r++) {
                    int m = m0 + wm * 64 + i * 16 + quad * 4 + r;
                    float qt = acc[i][j][r] + b + (float)m * invf;
                    float sn, cs;
                    sincos_hw(qt, &sn, &cs);
                    size_t base = ((size_t)hh * L + m) * HDE;
                    dst[base + 64 + jj] = f2b(sc * cs);
                    dst[base + 72 + jj] = f2b(sc * sn);
                }
        }
    }
}

// ---------------- flash attention: 32x32x16 MFMA, swapped QK^T (P lane-local),
// KVBLK=128, l-sum via MFMA with ones-B, NSPLIT=2 CU-pairing.
__launch_bounds__(256, 2)
__global__ void flash_attn(const ushort* __restrict__ Qe, const ushort* __restrict__ Ke,
                           const ushort* __restrict__ Vte,
                           ushort* __restrict__ Opart, float* __restrict__ ml) {
    const int b = blockIdx.x;
    const int xcd = b & 7;
    const int r = b >> 3;                    // 0..63 per XCD
    const int idx = r & 31, sub = r >> 5;    // r and r+32 land on the same CU
    const int hbit = idx >> 4, c0i = idx & 15;
    const int c = sub ? 15 - c0i : c0i;      // complementary chunk sizes pair up
    const int z = sub;
    const int h = xcd * 2 + hbit;
    const int tid = threadIdx.x;
    const int wave = tid >> 6, lane = tid & 63;
    const int ln32 = lane & 31, hf = lane >> 5;

    const int nT = c + 1;                    // 64-key tiles [z*(c+1), (z+1)*(c+1))
    const int s0 = z * nT;
    const int nR = (nT + 1) >> 1;            // 128-key rounds
    const int qw = c * 128 + wave * 32;      // wave's 32-row q strip

    __shared__ ushort Kl[128 * KLS];         // 26.6 KB
    __shared__ ushort Vt[64 * VT2];          // 17.4 KB

    const ushort* Kh = Ke + (size_t)h * L * HDE;
    const ushort* Vh = Vte + (size_t)h * HD * L;
    const ushort* Qh = Qe + (size_t)h * L * HDE;
    ushort* Op = Opart + (size_t)z * L * D;
    float* mlp = ml + (size_t)z * NH * L + (size_t)h * L;

    bf16x8 onesv;
#pragma unroll
    for (int i = 0; i < 8; i++) onesv[i] = (short)0x3F80;   // bf16 1.0

    // Q B-frags (col=q=ln32, contract c = cc*16 + hf*8 + j), loaded once
    bf16x8 qa[6];
#pragma unroll
    for (int cc = 0; cc < 6; cc++)
        qa[cc] = *(const bf16x8*)(Qh + (size_t)(qw + ln32) * HDE + cc * 16 + hf * 8);

    f32x16 o[2], olv;
#pragma unroll
    for (int i = 0; i < 16; i++) { o[0][i] = 0.f; o[1][i] = 0.f; olv[i] = 0.f; }

    // staging geometry (constant per thread)
    int rowk[6], colk[6];
#pragma unroll
    for (int ii = 0; ii < 6; ii++) {
        int ix = ii * 256 + tid;             // 1536 = 128 rows x 12 16B-chunks
        rowk[ii] = ix / 12; colk[ii] = ix - rowk[ii] * 12;
    }
    int dv[4], cv[4];
#pragma unroll
    for (int ii = 0; ii < 4; ii++) {
        int ix = ii * 256 + tid;             // 1024 = 64 d-rows x 16 16B-chunks
        dv[ii] = ix >> 4; cv[ii] = ix & 15;
    }

    bf16x8 kreg[6], vreg[4];
    {
        int kk = s0 * 64;
#pragma unroll
        for (int ii = 0; ii < 6; ii++)
            kreg[ii] = *(const bf16x8*)(Kh + (size_t)(kk + rowk[ii]) * HDE + colk[ii] * 8);
#pragma unroll
        for (int ii = 0; ii < 4; ii++)
            vreg[ii] = *(const bf16x8*)(Vh + (size_t)dv[ii] * L + kk + cv[ii] * 8);
    }

    for (int rr = 0; rr < nR; rr++) {
        const int tk0 = (s0 + rr * 2) * 64;
        __syncthreads();
#pragma unroll
        for (int ii = 0; ii < 6; ii++)
            *(bf16x8*)(&Kl[rowk[ii] * KLS + colk[ii] * 8]) = kreg[ii];
#pragma unroll
        for (int ii = 0; ii < 4; ii++)
            *(bf16x8*)(&Vt[dv[ii] * VT2 + cv[ii] * 8]) = vreg[ii];
        __syncthreads();

        if (rr + 1 < nR) {                   // prefetch next 128-key round
            int kk = tk0 + 128;
#pragma unroll
            for (int ii = 0; ii < 6; ii++)
                kreg[ii] = *(const bf16x8*)(Kh + (size_t)(kk + rowk[ii]) * HDE + colk[ii] * 8);
#pragma unroll
            for (int ii = 0; ii < 4; ii++)
                vreg[ii] = *(const bf16x8*)(Vh + (size_t)dv[ii] * L + kk + cv[ii] * 8);
        }

#pragma unroll
        for (int hb = 0; hb < 2; hb++) {
            const int tt = rr * 2 + hb;
            const int k0 = tk0 + hb * 64;
            if (tt < nT && k0 < qw + 32) {   // wave-uniform skip
                // QK^T swapped: s2[kb] = K_tile(32k x 96c) . Q^T -> D[k][q], col=q=ln32
                f32x16 s2[2];
#pragma unroll
                for (int i = 0; i < 16; i++) { s2[0][i] = 0.f; s2[1][i] = 0.f; }
                __builtin_amdgcn_s_setprio(1);
#pragma unroll
                for (int kb = 0; kb < 2; kb++)
#pragma unroll
                    for (int cc = 0; cc < 6; cc++) {
                        bf16x8 kf = *(const bf16x8*)(&Kl[(hb * 64 + kb * 32 + ln32) * KLS + cc * 16 + hf * 8]);
                        s2[kb] = __builtin_amdgcn_mfma_f32_32x32x16_bf16(kf, qa[cc], s2[kb], 0, 0, 0);
                    }
                __builtin_amdgcn_s_setprio(0);

                if (k0 + 63 > qw) {          // diagonal region: causal mask
#pragma unroll
                    for (int kb = 0; kb < 2; kb++)
#pragma unroll
                        for (int rg = 0; rg < 16; rg++) {
                            int key = k0 + kb * 32 + (rg & 3) + 8 * (rg >> 2) + 4 * hf;
                            if (key > qw + ln32) s2[kb][rg] = -1e30f;
                        }
                }

                // P = exp(s) in place (scores bounded; no max, no rescale)
#pragma unroll
                for (int kb = 0; kb < 2; kb++)
#pragma unroll
                    for (int rg = 0; rg < 16; rg++)
                        s2[kb][rg] = __expf(s2[kb][rg]);

                // pack P->bf16 pairs (per t-quad: X = regs 4t,4t+1; Y = 4t+2,4t+3)
                unsigned Xp[2][4], Yp[2][4];
#pragma unroll
                for (int kb = 0; kb < 2; kb++)
#pragma unroll
                    for (int tq = 0; tq < 4; tq++) {
                        asm("v_cvt_pk_bf16_f32 %0, %1, %2"
                            : "=v"(Xp[kb][tq]) : "v"(s2[kb][4 * tq + 0]), "v"(s2[kb][4 * tq + 1]));
                        asm("v_cvt_pk_bf16_f32 %0, %1, %2"
                            : "=v"(Yp[kb][tq]) : "v"(s2[kb][4 * tq + 2]), "v"(s2[kb][4 * tq + 3]));
                    }

                // build PV A-frags via half-exchange: pa[m] covers k = m*16 + hf*8 + j
                bf16x8 pa[4];
#pragma unroll
                for (int m = 0; m < 4; m++) {
                    int kb = m >> 1, te = 2 * (m & 1), to = te + 1;
                    unsigned x0 = Xp[kb][te], x1 = Xp[kb][to];
                    unsigned y0 = Yp[kb][te], y1 = Yp[kb][to];
                    asm("v_permlane32_swap_b32 %0, %1" : "+v"(x0), "+v"(x1));
                    asm("v_permlane32_swap_b32 %0, %1" : "+v"(y0), "+v"(y1));
                    union { unsigned u[4]; bf16x8 v; } pb;
                    pb.u[0] = x0; pb.u[1] = y0; pb.u[2] = x1; pb.u[3] = y1;
                    pa[m] = pb.v;
                }

                // PV: o[db] (rows q, cols d = db*32+ln32); l-sum via ones-B MFMA
                __builtin_amdgcn_s_setprio(1);
#pragma unroll
                for (int m = 0; m < 4; m++) {
#pragma unroll
                    for (int db = 0; db < 2; db++) {
                        bf16x8 vf = *(const bf16x8*)(&Vt[(db * 32 + ln32) * VT2 + hb * 64 + m * 16 + hf * 8]);
                        o[db] = __builtin_amdgcn_mfma_f32_32x32x16_bf16(pa[m], vf, o[db], 0, 0, 0);
                    }
                    olv = __builtin_amdgcn_mfma_f32_32x32x16_bf16(pa[m], onesv, olv, 0, 0, 0);
                }
                __builtin_amdgcn_s_setprio(0);
            }
        }
    }

    // l write: olv row q = (rg&3)+8*(rg>>2)+4*hf, all cols equal -> col 0 writes
    if (ln32 == 0) {
#pragma unroll
        for (int rg = 0; rg < 16; rg++) {
            int q = qw + (rg & 3) + 8 * (rg >> 2) + 4 * hf;
            mlp[q] = olv[rg];
        }
    }
    // write partial O: lane col d = db*32+ln32, row q = (rg&3)+8*(rg>>2)+4*hf
#pragma unroll
    for (int db = 0; db < 2; db++)
#pragma unroll
        for (int rg = 0; rg < 16; rg++) {
            int q = qw + (rg & 3) + 8 * (rg >> 2) + 4 * hf;
            Op[(size_t)q * D + h * HD + db * 32 + ln32] = f2b(o[db][rg]);
        }
}

// ---------------- combine the split partials -> normalized AOb (reads Opart ONCE)
__global__ void comb_kernel(const ushort* __restrict__ Opart, const float* __restrict__ ml,
                            ushort* __restrict__ AOb) {
    int q = blockIdx.x;
    int t = threadIdx.x;                     // dims t*4..t*4+3, h = t>>4
    int h = t >> 4;
    float lsum = 0.f;
#pragma unroll
    for (int zz = 0; zz < NSPLIT; zz++)
        lsum += ml[(size_t)zz * NH * L + (size_t)h * L + q];
    float inv = 1.f / lsum;
    size_t idx = (size_t)q * D + t * 4;
    float ox = 0.f, oy = 0.f, oz = 0.f, ow = 0.f;
#pragma unroll
    for (int zz = 0; zz < NSPLIT; zz++) {
        ushort4 a = *(const ushort4*)(Opart + (size_t)zz * L * D + idx);
        ox += b2f(a.x); oy += b2f(a.y); oz += b2f(a.z); ow += b2f(a.w);
    }
    ushort4 o;
    o.x = f2b(ox * inv); o.y = f2b(oy * inv);
    o.z = f2b(oz * inv); o.w = f2b(ow * inv);
    *(ushort4*)(AOb + idx) = o;
}

// ---------------- Wo MFMA GEMM: O2 fp32 = AOb @ Wot.
// 128x64 output tiles -> grid 16x16 = 256 blocks (one per CU; the old 128-block
// 128x128 tiling left half the machine idle). Static double-buffer, gld_lds16.
__launch_bounds__(256)
__global__ void wo_gemm(const ushort* __restrict__ Ab, const ushort* __restrict__ Bt,
                        float* __restrict__ C) {
    __shared__ ushort As0[128 * 32], Bs0[64 * 32];
    __shared__ ushort As1[128 * 32], Bs1[64 * 32];
    const int tid = threadIdx.x;
    const int wave = tid >> 6, lane = tid & 63, quad = lane >> 4, ln16 = lane & 15;
    const int m0 = blockIdx.y * 128, n0 = blockIdx.x * 64;
    f32x4 acc[2][4];
#pragma unroll
    for (int i = 0; i < 2; i++)
#pragma unroll
        for (int j = 0; j < 4; j++) acc[i][j] = (f32x4){0.f, 0.f, 0.f, 0.f};

    auto stage = [&](int kt, ushort* Asb, ushort* Bsb) {
#pragma unroll
        for (int i = 0; i < 2; i++) {        // A: 128x32 = 8KB = 2 issues
            int idx = i * 256 + tid;
            int r2 = idx >> 2, cc = idx & 3;
            gld_lds16(Ab + (size_t)(m0 + r2) * D + kt + cc * 8, &Asb[idx * 8]);
        }
        {                                    // B: 64x32 = 4KB = 1 issue
            int r2 = tid >> 2, cc = tid & 3;
            gld_lds16(Bt + (size_t)(n0 + r2) * D + kt + cc * 8, &Bsb[tid * 8]);
        }
    };
    auto compute = [&](const ushort* Asb, const ushort* Bsb) {
        bf16x8 af[2], bfr[4];
#pragma unroll
        for (int i = 0; i < 2; i++)
            af[i] = *(const bf16x8*)(&Asb[(wave * 32 + i * 16 + ln16) * 32 + quad * 8]);
#pragma unroll
        for (int j = 0; j < 4; j++)
            bfr[j] = *(const bf16x8*)(&Bsb[(j * 16 + ln16) * 32 + quad * 8]);
#pragma unroll
        for (int i = 0; i < 2; i++)
#pragma unroll
            for (int j = 0; j < 4; j++)
                acc[i][j] = __builtin_amdgcn_mfma_f32_16x16x32_bf16(af[i], bfr[j], acc[i][j], 0, 0, 0);
    };

    stage(0, As0, Bs0);
    __syncthreads();
    for (int kt = 0; kt < D; kt += 64) {
        stage(kt + 32, As1, Bs1);
        compute(As0, Bs0);
        __syncthreads();
        if (kt + 64 < D) stage(kt + 64, As0, Bs0);
        compute(As1, Bs1);
        __syncthreads();
    }
#pragma unroll
    for (int i = 0; i < 2; i++)
#pragma unroll
        for (int j = 0; j < 4; j++)
#pragma unroll
            for (int r = 0; r < 4; r++) {
                int m = m0 + wave * 32 + i * 16 + quad * 4 + r;
                int n = n0 + j * 16 + ln16;
                C[(size_t)m * D + n] = acc[i][j][r];
            }
}

// ---------------- residual + LayerNorm (wave-shuffle reduce) + x_imag copy
__global__ void ln_kernel(const float* __restrict__ xr, const float* __restrict__ o2,
                          const float* __restrict__ gamma, const float* __restrict__ beta,
                          float* __restrict__ outp, const float4* __restrict__ xi4,
                          float4* __restrict__ out1) {
    int l = blockIdx.x;
    int tid = threadIdx.x;
    int wave = tid >> 6;
    __shared__ float red[8];
    float hv[4];
    float s = 0.f;
#pragma unroll
    for (int i = 0; i < 4; i++) {
        int c = tid + i * 256;
        hv[i] = xr[(size_t)l * D + c] + o2[(size_t)l * D + c];
        s += hv[i];
    }
    out1[(size_t)l * (D / 4) + tid] = xi4[(size_t)l * (D / 4) + tid];
#pragma unroll
    for (int off = 1; off < 64; off <<= 1) s += __shfl_xor(s, off);
    if ((tid & 63) == 0) red[wave] = s;
    __syncthreads();
    float mu = (red[0] + red[1] + red[2] + red[3]) * (1.f / D);
    float v = 0.f;
#pragma unroll
    for (int i = 0; i < 4; i++) { float d = hv[i] - mu; v += d * d; }
#pragma unroll
    for (int off = 1; off < 64; off <<= 1) v += __shfl_xor(v, off);
    __syncthreads();
    if ((tid & 63) == 0) red[4 + wave] = v;
    __syncthreads();
    float rstd = rsqrtf((red[4] + red[5] + red[6] + red[7]) * (1.f / D) + 1e-5f);
#pragma unroll
    for (int i = 0; i < 4; i++) {
        int c = tid + i * 256;
        outp[(size_t)l * D + c] = (hv[i] - mu) * rstd * gamma[c] + beta[c];
    }
}

extern "C" void kernel_launch(void* const* d_in, const int* in_sizes, int n_in,
                              void* d_out, int out_size, void* d_ws, size_t ws_size,
                              hipStream_t stream) {
    const float* xr    = (const float*)d_in[0];
    const float* xi    = (const float*)d_in[1];
    const float* Wq    = (const float*)d_in[2];
    const float* Wk    = (const float*)d_in[3];
    const float* Wv    = (const float*)d_in[4];
    const float* Wqp   = (const float*)d_in[5];
    const float* bqp   = (const float*)d_in[6];
    const float* Wkp   = (const float*)d_in[7];
    const float* bkp   = (const float*)d_in[8];
    const float* Wo    = (const float*)d_in[9];
    const float* alpha = (const float*)d_in[10];
    const float* gamma = (const float*)d_in[11];
    const float* beta  = (const float*)d_in[12];

    const size_t LD = (size_t)L * D;
    const size_t MB = 1024 * 1024;

    // d_out A [0,8MB): xib(4, dead after qkv z=3) -> AOb(4) | Wot(2) | Wtq(2)
    //                  -> LN fp32 output (last)
    // d_out B [8,16MB): xrb(4) | Wtk(2) | Wtv(2) -> x_imag copy (last, via ln)
    char* A8 = (char*)d_out;
    char* B8 = A8 + LD * 4;
    ushort* xib = (ushort*)A8;
    ushort* AOb = (ushort*)A8;
    ushort* Wot = (ushort*)(A8 + 4 * MB);
    ushort* Wtq = (ushort*)(A8 + 6 * MB);
    ushort* xrb = (ushort*)B8;
    ushort* Wtk = (ushort*)(B8 + 4 * MB);
    ushort* Wtv = (ushort*)(B8 + 6 * MB);
    float* outf = (float*)d_out;

    // ws: Qe(6.29) | Ke(6.29) | Vte(4.19, transposed [h][d][L]) | Wqpkt(0.52)
    //     | Opart(8) | ml(0.26).  O2 fp32 overlays ws[0,8MB) (Qe/Ke dead after flash).
    ushort* Qe = (ushort*)d_ws;
    ushort* Ke = Qe + (size_t)NH * L * HDE;
    ushort* Ve = Ke + (size_t)NH * L * HDE;
    ushort* Wqpkt = Ve + (size_t)NH * L * HD;
    ushort* Opart = Wqpkt + (size_t)256 * D;            // NSPLIT x L*D bf16 = 8 MB
    float*  mlbuf = (float*)(Opart + (size_t)NSPLIT * LD);
    float*  O2 = (float*)d_ws;

    prep_kernel<<<8576, 256, 0, stream>>>(xr, xi, xrb, xib,
                                          Wq, Wk, Wv, Wo, Wqp, Wkp,
                                          Wtq, Wtk, Wtv, Wot, Wqpkt, Qe, Ke);

    qkv_gemm<<<dim3(8, 16, 4), 256, 0, stream>>>(xrb, xib, Wtq, Wtk, Wtv, Wqpkt,
                                                 Qe, Ke, Ve, alpha, bqp, bkp);

    flash_attn<<<512, 256, 0, stream>>>(Qe, Ke, Ve, Opart, mlbuf);

    comb_kernel<<<L, 256, 0, stream>>>(Opart, mlbuf, AOb);

    wo_gemm<<<dim3(16, 16), 256, 0, stream>>>(AOb, Wot, O2);

    ln_kernel<<<L, 256, 0, stream>>>(xr, O2, gamma, beta, outf,
                                     (const float4*)xi, (float4*)(B8));
}

// Round 9
// 176.905 us; speedup vs baseline: 1.0835x; 1.0202x over previous
//
#include <hip/hip_runtime.h>
#include <hip/hip_bf16.h>
#include <math.h>

#define L 2048
#define D 1024
#define NH 16
#define HD 64
#define P 128
#define HDE 96                              /* extended head dim 80, padded to 96 */
#define CONTENT_SCALE 0.125f                /* 1/sqrt(64) */
#define PHASE_SCALE   0.35355339059327373f  /* 1/sqrt(8) */
#define KLS 104                             /* Kl LDS stride */
#define VT2 136                             /* Vt LDS stride (128 cols + pad) */
#define NSPLIT 2

typedef short bf16x8 __attribute__((ext_vector_type(8)));
typedef float f32x4 __attribute__((ext_vector_type(4)));
typedef float f32x16 __attribute__((ext_vector_type(16)));

__device__ inline ushort f2b(float x) {
    __hip_bfloat16 b = __float2bfloat16(x);
    return *(ushort*)&b;
}
__device__ inline float b2f(ushort u) {
    unsigned v = (unsigned)u << 16;
    union { unsigned u; float f; } c; c.u = v; return c.f;
}

// hardware sincos: v_sin/v_cos take REVOLUTIONS; reduce with fract
__device__ inline void sincos_hw(float ang, float* sn, float* cs) {
    float rev = ang * 0.15915494309189535f;
    rev -= floorf(rev);
    *sn = __builtin_amdgcn_sinf(rev);
    *cs = __builtin_amdgcn_cosf(rev);
}

// async global->LDS, 16B per lane; LDS dest = wave-uniform base + lane*16
__device__ inline void gld_lds16(const void* g, void* l) {
    __builtin_amdgcn_global_load_lds(
        (const __attribute__((address_space(1))) unsigned int*)g,
        (__attribute__((address_space(3))) unsigned int*)l,
        16, 0, 0);
}

// ---------------- fused prep: [0,4096) cvt fp32->bf16, [4096,8448) transpose W,
// [8448,8576) zero Qe/Ke pad cols 80..95
__global__ void prep_kernel(const float* __restrict__ xr, const float* __restrict__ xi,
                            ushort* __restrict__ xrb, ushort* __restrict__ xib,
                            const float* __restrict__ W0, const float* __restrict__ W1,
                            const float* __restrict__ W2, const float* __restrict__ W3,
                            const float* __restrict__ W4, const float* __restrict__ W5,
                            ushort* __restrict__ T0, ushort* __restrict__ T1,
                            ushort* __restrict__ T2, ushort* __restrict__ T3,
                            ushort* __restrict__ Tp,
                            ushort* __restrict__ Qe, ushort* __restrict__ Ke) {
    __shared__ float tile[32][33];
    const int b = blockIdx.x;
    const int tid = threadIdx.x;
    if (b < 4096) {                          // cvt: 2 tensors x 2048 blocks
        const float4* src = (b >> 11) ? (const float4*)xi : (const float4*)xr;
        ushort4* dst = (b >> 11) ? (ushort4*)xib : (ushort4*)xrb;
        int i = ((b & 2047) << 8) + tid;
        float4 v = src[i];
        ushort4 o;
        o.x = f2b(v.x); o.y = f2b(v.y); o.z = f2b(v.z); o.w = f2b(v.w);
        dst[i] = o;
    } else if (b < 8448) {                   // transpose+convert weights
        int w = b - 4096;
        const float* W; ushort* T; int ncols, n0, k0;
        if (w < 4096) {
            int z = w >> 10, t = w & 1023;
            n0 = (t & 31) * 32; k0 = (t >> 5) * 32; ncols = D;
            W = (z == 0) ? W0 : ((z == 1) ? W1 : ((z == 2) ? W2 : W3));
            T = (z == 0) ? T0 : ((z == 1) ? T1 : ((z == 2) ? T2 : T3));
        } else {
            int w2 = w - 4096;
            int z = w2 >> 7, t = w2 & 127;
            n0 = (t & 3) * 32; k0 = (t >> 2) * 32; ncols = P;
            W = z ? W5 : W4;
            T = Tp + (size_t)z * P * D;
        }
        int tx = tid & 31, ty = tid >> 5;
#pragma unroll
        for (int i = 0; i < 4; i++)
            tile[ty + i * 8][tx] = W[(size_t)(k0 + ty + i * 8) * ncols + n0 + tx];
        __syncthreads();
#pragma unroll
        for (int i = 0; i < 4; i++)
            T[(size_t)(n0 + ty + i * 8) * D + k0 + tx] = f2b(tile[tx][ty + i * 8]);
    } else {                                 // zpad
        int i = (b - 8448) * 256 + tid;      // 0 .. NH*L-1
        size_t base = (size_t)i * HDE + 80;
        uint4 z4 = make_uint4(0, 0, 0, 0);
        *(uint4*)(Qe + base) = z4;
        *(uint4*)(Qe + base + 8) = z4;
        *(uint4*)(Ke + base) = z4;
        *(uint4*)(Ke + base + 8) = z4;
    }
}

// ---------------- fused QKV + phase MFMA GEMM. z=0..2: Q/K/V; z=3: phase (x<2)
// 512 threads / 8 waves (2x4 wave grid, 64x32 per wave): 16 waves/CU at 2
// blocks/CU (was 8) -- cross-block overlap hides the per-barrier vmcnt drain.
// XOR-swizzled staging (global-source pre-swizzle; linear gld_lds dest) kills
// the 8-way ds_read_b128 bank conflict (rows r, r+2 shared a bank at 64B stride).
__launch_bounds__(512)
__global__ void qkv_gemm(const ushort* __restrict__ Ab, const ushort* __restrict__ xib,
                         const ushort* __restrict__ Wtq, const ushort* __restrict__ Wtk,
                         const ushort* __restrict__ Wtv, const ushort* __restrict__ Wtp,
                         ushort* __restrict__ Qe, ushort* __restrict__ Ke,
                         ushort* __restrict__ Ve, const float* __restrict__ alpha,
                         const float* __restrict__ bqp, const float* __restrict__ bkp) {
    const int z = blockIdx.z;
    if (z == 3 && blockIdx.x >= 2) return;
    const ushort* At = (z == 3) ? xib : Ab;
    const ushort* Bt = (z == 0) ? Wtq : ((z == 1) ? Wtk : ((z == 2) ? Wtv : Wtp));
    __shared__ ushort As0[128 * 32], Bs0[128 * 32];
    __shared__ ushort As1[128 * 32], Bs1[128 * 32];
    const int tid = threadIdx.x;
    const int wave = tid >> 6, lane = tid & 63, quad = lane >> 4, ln16 = lane & 15;
    const int wm = wave >> 2, wn = wave & 3;
    const int m0 = blockIdx.y * 128, n0 = blockIdx.x * 128;
    f32x4 acc[4][2];
#pragma unroll
    for (int i = 0; i < 4; i++)
#pragma unroll
        for (int j = 0; j < 2; j++) acc[i][j] = (f32x4){0.f, 0.f, 0.f, 0.f};

    // staging: 512 threads x 16B = one 128x32 tile per call; source pre-swizzled
    const int r2 = tid >> 2, cc = tid & 3;
    const int cc2 = cc ^ ((r2 >> 1) & 3);
    const int swr = (ln16 >> 1) & 3;         // read-side swizzle (row>>1)&3

    auto stage = [&](int kt, ushort* Asb, ushort* Bsb) {
        gld_lds16(At + (size_t)(m0 + r2) * D + kt + cc2 * 8, &Asb[tid * 8]);
        gld_lds16(Bt + (size_t)(n0 + r2) * D + kt + cc2 * 8, &Bsb[tid * 8]);
    };
    auto compute = [&](const ushort* Asb, const ushort* Bsb) {
        bf16x8 af[4], bfr[2];
#pragma unroll
        for (int t = 0; t < 4; t++)
            af[t] = *(const bf16x8*)(&Asb[(wm * 64 + t * 16 + ln16) * 32 + (quad ^ swr) * 8]);
#pragma unroll
        for (int j = 0; j < 2; j++)
            bfr[j] = *(const bf16x8*)(&Bsb[(wn * 32 + j * 16 + ln16) * 32 + (quad ^ swr) * 8]);
#pragma unroll
        for (int i = 0; i < 4; i++)
#pragma unroll
            for (int j = 0; j < 2; j++)
                acc[i][j] = __builtin_amdgcn_mfma_f32_16x16x32_bf16(af[i], bfr[j], acc[i][j], 0, 0, 0);
    };

    stage(0, As0, Bs0);
    __syncthreads();
    for (int kt = 0; kt < D; kt += 64) {
        stage(kt + 32, As1, Bs1);            // write b1 (readers done at prev barrier)
        compute(As0, Bs0);                   // read b0 (no alias with b1 writes)
        __syncthreads();
        if (kt + 64 < D) stage(kt + 64, As0, Bs0);
        compute(As1, Bs1);
        __syncthreads();
    }

    if (z == 2) {                            // V epilogue -> transposed Vte[h][d][L]
        int hn = (n0 >> 6) + (wn >> 1);
#pragma unroll
        for (int i = 0; i < 4; i++)
#pragma unroll
            for (int j = 0; j < 2; j++) {
                int d = (wn & 1) * 32 + j * 16 + ln16;
                int m = m0 + wm * 64 + i * 16 + quad * 4;
                ushort4 pk;
                pk.x = f2b(acc[i][j][0]); pk.y = f2b(acc[i][j][1]);
                pk.z = f2b(acc[i][j][2]); pk.w = f2b(acc[i][j][3]);
                *(ushort4*)(Ve + ((size_t)hn * HD + d) * L + m) = pk;
            }
    } else if (z < 2) {                      // Q/K epilogue, row-major [h][m][c]
        int hn = (n0 >> 6) + (wn >> 1);
        float s = (z == 0) ? (1.f - 1.f / (1.f + __expf(-alpha[hn]))) * CONTENT_SCALE : 1.f;
        ushort* dst = (z == 0) ? Qe : Ke;
#pragma unroll
        for (int i = 0; i < 4; i++)
#pragma unroll
            for (int j = 0; j < 2; j++) {
                int dcol = (wn & 1) * 32 + j * 16 + ln16;
#pragma unroll
                for (int r = 0; r < 4; r++) {
                    int m = m0 + wm * 64 + i * 16 + quad * 4 + r;
                    dst[((size_t)hn * L + m) * HDE + dcol] = f2b(acc[i][j][r] * s);
                }
            }
    } else {                                 // phase epilogue -> Qe/Ke cols 64..79
#pragma unroll
        for (int j = 0; j < 2; j++) {
            int cg = n0 + wn * 32 + j * 16 + ln16;   // 0..255
            int isQ = cg < P;
            int c = cg & (P - 1);
            int hh = c >> 3, jj = c & 7;
            float b = isQ ? bqp[c] : bkp[c];
            float sc = isQ ? (1.f / (1.f + __expf(-alpha[hh]))) * PHASE_SCALE : 1.f;
            float invf = __expf(-((float)(c & ~1) / 128.f) * 9.210340371976184f);
            ushort* dst = isQ ? Qe : Ke;
#pragma unroll
            for (int i = 0; i < 4; i++)
#pragma unroll
                for (int r = 0; r < 4; r++) {
                    int m = m0 + wm * 64 + i * 16 + quad * 4 + r;
                    float qt = acc[i][j][r] + b + (float)m * invf;
                    float sn, cs;
                    sincos_hw(qt, &sn, &cs);
                    size_t base = ((size_t)hh * L + m) * HDE;
                    dst[base + 64 + jj] = f2b(sc * cs);
                    dst[base + 72 + jj] = f2b(sc * sn);
                }
        }
    }
}

// ---------------- flash attention: 32x32x16 MFMA, swapped QK^T (P lane-local),
// KVBLK=128, l-sum via MFMA with ones-B, NSPLIT=2 CU-pairing.
__launch_bounds__(256, 2)
__global__ void flash_attn(const ushort* __restrict__ Qe, const ushort* __restrict__ Ke,
                           const ushort* __restrict__ Vte,
                           ushort* __restrict__ Opart, float* __restrict__ ml) {
    const int b = blockIdx.x;
    const int xcd = b & 7;
    const int r = b >> 3;                    // 0..63 per XCD
    const int idx = r & 31, sub = r >> 5;    // r and r+32 land on the same CU
    const int hbit = idx >> 4, c0i = idx & 15;
    const int c = sub ? 15 - c0i : c0i;      // complementary chunk sizes pair up
    const int z = sub;
    const int h = xcd * 2 + hbit;
    const int tid = threadIdx.x;
    const int wave = tid >> 6, lane = tid & 63;
    const int ln32 = lane & 31, hf = lane >> 5;

    const int nT = c + 1;                    // 64-key tiles [z*(c+1), (z+1)*(c+1))
    const int s0 = z * nT;
    const int nR = (nT + 1) >> 1;            // 128-key rounds
    const int qw = c * 128 + wave * 32;      // wave's 32-row q strip

    __shared__ ushort Kl[128 * KLS];         // 26.6 KB
    __shared__ ushort Vt[64 * VT2];          // 17.4 KB

    const ushort* Kh = Ke + (size_t)h * L * HDE;
    const ushort* Vh = Vte + (size_t)h * HD * L;
    const ushort* Qh = Qe + (size_t)h * L * HDE;
    ushort* Op = Opart + (size_t)z * L * D;
    float* mlp = ml + (size_t)z * NH * L + (size_t)h * L;

    bf16x8 onesv;
#pragma unroll
    for (int i = 0; i < 8; i++) onesv[i] = (short)0x3F80;   // bf16 1.0

    // Q B-frags (col=q=ln32, contract c = cc*16 + hf*8 + j), loaded once
    bf16x8 qa[6];
#pragma unroll
    for (int cc = 0; cc < 6; cc++)
        qa[cc] = *(const bf16x8*)(Qh + (size_t)(qw + ln32) * HDE + cc * 16 + hf * 8);

    f32x16 o[2], olv;
#pragma unroll
    for (int i = 0; i < 16; i++) { o[0][i] = 0.f; o[1][i] = 0.f; olv[i] = 0.f; }

    // staging geometry (constant per thread)
    int rowk[6], colk[6];
#pragma unroll
    for (int ii = 0; ii < 6; ii++) {
        int ix = ii * 256 + tid;             // 1536 = 128 rows x 12 16B-chunks
        rowk[ii] = ix / 12; colk[ii] = ix - rowk[ii] * 12;
    }
    int dv[4], cv[4];
#pragma unroll
    for (int ii = 0; ii < 4; ii++) {
        int ix = ii * 256 + tid;             // 1024 = 64 d-rows x 16 16B-chunks
        dv[ii] = ix >> 4; cv[ii] = ix & 15;
    }

    bf16x8 kreg[6], vreg[4];
    {
        int kk = s0 * 64;
#pragma unroll
        for (int ii = 0; ii < 6; ii++)
            kreg[ii] = *(const bf16x8*)(Kh + (size_t)(kk + rowk[ii]) * HDE + colk[ii] * 8);
#pragma unroll
        for (int ii = 0; ii < 4; ii++)
            vreg[ii] = *(const bf16x8*)(Vh + (size_t)dv[ii] * L + kk + cv[ii] * 8);
    }

    for (int rr = 0; rr < nR; rr++) {
        const int tk0 = (s0 + rr * 2) * 64;
        __syncthreads();
#pragma unroll
        for (int ii = 0; ii < 6; ii++)
            *(bf16x8*)(&Kl[rowk[ii] * KLS + colk[ii] * 8]) = kreg[ii];
#pragma unroll
        for (int ii = 0; ii < 4; ii++)
            *(bf16x8*)(&Vt[dv[ii] * VT2 + cv[ii] * 8]) = vreg[ii];
        __syncthreads();

        if (rr + 1 < nR) {                   // prefetch next 128-key round
            int kk = tk0 + 128;
#pragma unroll
            for (int ii = 0; ii < 6; ii++)
                kreg[ii] = *(const bf16x8*)(Kh + (size_t)(kk + rowk[ii]) * HDE + colk[ii] * 8);
#pragma unroll
            for (int ii = 0; ii < 4; ii++)
                vreg[ii] = *(const bf16x8*)(Vh + (size_t)dv[ii] * L + kk + cv[ii] * 8);
        }

#pragma unroll
        for (int hb = 0; hb < 2; hb++) {
            const int tt = rr * 2 + hb;
            const int k0 = tk0 + hb * 64;
            if (tt < nT && k0 < qw + 32) {   // wave-uniform skip
                // QK^T swapped: s2[kb] = K_tile(32k x 96c) . Q^T -> D[k][q], col=q=ln32
                f32x16 s2[2];
#pragma unroll
                for (int i = 0; i < 16; i++) { s2[0][i] = 0.f; s2[1][i] = 0.f; }
                __builtin_amdgcn_s_setprio(1);
#pragma unroll
                for (int kb = 0; kb < 2; kb++)
#pragma unroll
                    for (int cc = 0; cc < 6; cc++) {
                        bf16x8 kf = *(const bf16x8*)(&Kl[(hb * 64 + kb * 32 + ln32) * KLS + cc * 16 + hf * 8]);
                        s2[kb] = __builtin_amdgcn_mfma_f32_32x32x16_bf16(kf, qa[cc], s2[kb], 0, 0, 0);
                    }
                __builtin_amdgcn_s_setprio(0);

                if (k0 + 63 > qw) {          // diagonal region: causal mask
#pragma unroll
                    for (int kb = 0; kb < 2; kb++)
#pragma unroll
                        for (int rg = 0; rg < 16; rg++) {
                            int key = k0 + kb * 32 + (rg & 3) + 8 * (rg >> 2) + 4 * hf;
                            if (key > qw + ln32) s2[kb][rg] = -1e30f;
                        }
                }

                // P = exp(s) in place (scores bounded; no max, no rescale)
#pragma unroll
                for (int kb = 0; kb < 2; kb++)
#pragma unroll
                    for (int rg = 0; rg < 16; rg++)
                        s2[kb][rg] = __expf(s2[kb][rg]);

                // pack P->bf16 pairs (per t-quad: X = regs 4t,4t+1; Y = 4t+2,4t+3)
                unsigned Xp[2][4], Yp[2][4];
#pragma unroll
                for (int kb = 0; kb < 2; kb++)
#pragma unroll
                    for (int tq = 0; tq < 4; tq++) {
                        asm("v_cvt_pk_bf16_f32 %0, %1, %2"
                            : "=v"(Xp[kb][tq]) : "v"(s2[kb][4 * tq + 0]), "v"(s2[kb][4 * tq + 1]));
                        asm("v_cvt_pk_bf16_f32 %0, %1, %2"
                            : "=v"(Yp[kb][tq]) : "v"(s2[kb][4 * tq + 2]), "v"(s2[kb][4 * tq + 3]));
                    }

                // build PV A-frags via half-exchange: pa[m] covers k = m*16 + hf*8 + j
                bf16x8 pa[4];
#pragma unroll
                for (int m = 0; m < 4; m++) {
                    int kb = m >> 1, te = 2 * (m & 1), to = te + 1;
                    unsigned x0 = Xp[kb][te], x1 = Xp[kb][to];
                    unsigned y0 = Yp[kb][te], y1 = Yp[kb][to];
                    asm("v_permlane32_swap_b32 %0, %1" : "+v"(x0), "+v"(x1));
                    asm("v_permlane32_swap_b32 %0, %1" : "+v"(y0), "+v"(y1));
                    union { unsigned u[4]; bf16x8 v; } pb;
                    pb.u[0] = x0; pb.u[1] = y0; pb.u[2] = x1; pb.u[3] = y1;
                    pa[m] = pb.v;
                }

                // PV: o[db] (rows q, cols d = db*32+ln32); l-sum via ones-B MFMA
                __builtin_amdgcn_s_setprio(1);
#pragma unroll
                for (int m = 0; m < 4; m++) {
#pragma unroll
                    for (int db = 0; db < 2; db++) {
                        bf16x8 vf = *(const bf16x8*)(&Vt[(db * 32 + ln32) * VT2 + hb * 64 + m * 16 + hf * 8]);
                        o[db] = __builtin_amdgcn_mfma_f32_32x32x16_bf16(pa[m], vf, o[db], 0, 0, 0);
                    }
                    olv = __builtin_amdgcn_mfma_f32_32x32x16_bf16(pa[m], onesv, olv, 0, 0, 0);
                }
                __builtin_amdgcn_s_setprio(0);
            }
        }
    }

    // l write: olv row q = (rg&3)+8*(rg>>2)+4*hf, all cols equal -> col 0 writes
    if (ln32 == 0) {
#pragma unroll
        for (int rg = 0; rg < 16; rg++) {
            int q = qw + (rg & 3) + 8 * (rg >> 2) + 4 * hf;
            mlp[q] = olv[rg];
        }
    }
    // write partial O: lane col d = db*32+ln32, row q = (rg&3)+8*(rg>>2)+4*hf
#pragma unroll
    for (int db = 0; db < 2; db++)
#pragma unroll
        for (int rg = 0; rg < 16; rg++) {
            int q = qw + (rg & 3) + 8 * (rg >> 2) + 4 * hf;
            Op[(size_t)q * D + h * HD + db * 32 + ln32] = f2b(o[db][rg]);
        }
}

// ---------------- combine the split partials -> normalized AOb (reads Opart ONCE)
__global__ void comb_kernel(const ushort* __restrict__ Opart, const float* __restrict__ ml,
                            ushort* __restrict__ AOb) {
    int q = blockIdx.x;
    int t = threadIdx.x;                     // dims t*4..t*4+3, h = t>>4
    int h = t >> 4;
    float lsum = 0.f;
#pragma unroll
    for (int zz = 0; zz < NSPLIT; zz++)
        lsum += ml[(size_t)zz * NH * L + (size_t)h * L + q];
    float inv = 1.f / lsum;
    size_t idx = (size_t)q * D + t * 4;
    float ox = 0.f, oy = 0.f, oz = 0.f, ow = 0.f;
#pragma unroll
    for (int zz = 0; zz < NSPLIT; zz++) {
        ushort4 a = *(const ushort4*)(Opart + (size_t)zz * L * D + idx);
        ox += b2f(a.x); oy += b2f(a.y); oz += b2f(a.z); ow += b2f(a.w);
    }
    ushort4 o;
    o.x = f2b(ox * inv); o.y = f2b(oy * inv);
    o.z = f2b(oz * inv); o.w = f2b(ow * inv);
    *(ushort4*)(AOb + idx) = o;
}

// ---------------- Wo MFMA GEMM: O2 fp32 = AOb @ Wot.
// 128x64 tiles, grid 16x16 = 256 blocks (1/CU). Static dbuf + XOR swizzle.
__launch_bounds__(256)
__global__ void wo_gemm(const ushort* __restrict__ Ab, const ushort* __restrict__ Bt,
                        float* __restrict__ C) {
    __shared__ ushort As0[128 * 32], Bs0[64 * 32];
    __shared__ ushort As1[128 * 32], Bs1[64 * 32];
    const int tid = threadIdx.x;
    const int wave = tid >> 6, lane = tid & 63, quad = lane >> 4, ln16 = lane & 15;
    const int m0 = blockIdx.y * 128, n0 = blockIdx.x * 64;
    const int swr = (ln16 >> 1) & 3;         // read-side swizzle (row>>1)&3
    f32x4 acc[2][4];
#pragma unroll
    for (int i = 0; i < 2; i++)
#pragma unroll
        for (int j = 0; j < 4; j++) acc[i][j] = (f32x4){0.f, 0.f, 0.f, 0.f};

    auto stage = [&](int kt, ushort* Asb, ushort* Bsb) {
#pragma unroll
        for (int i = 0; i < 2; i++) {        // A: 128x32 = 8KB = 2 issues
            int idx = i * 256 + tid;
            int r2 = idx >> 2, cc = idx & 3;
            int cc2 = cc ^ ((r2 >> 1) & 3);
            gld_lds16(Ab + (size_t)(m0 + r2) * D + kt + cc2 * 8, &Asb[idx * 8]);
        }
        {                                    // B: 64x32 = 4KB = 1 issue
            int r2 = tid >> 2, cc = tid & 3;
            int cc2 = cc ^ ((r2 >> 1) & 3);
            gld_lds16(Bt + (size_t)(n0 + r2) * D + kt + cc2 * 8, &Bsb[tid * 8]);
        }
    };
    auto compute = [&](const ushort* Asb, const ushort* Bsb) {
        bf16x8 af[2], bfr[4];
#pragma unroll
        for (int i = 0; i < 2; i++)
            af[i] = *(const bf16x8*)(&Asb[(wave * 32 + i * 16 + ln16) * 32 + (quad ^ swr) * 8]);
#pragma unroll
        for (int j = 0; j < 4; j++)
            bfr[j] = *(const bf16x8*)(&Bsb[(j * 16 + ln16) * 32 + (quad ^ swr) * 8]);
#pragma unroll
        for (int i = 0; i < 2; i++)
#pragma unroll
            for (int j = 0; j < 4; j++)
                acc[i][j] = __builtin_amdgcn_mfma_f32_16x16x32_bf16(af[i], bfr[j], acc[i][j], 0, 0, 0);
    };

    stage(0, As0, Bs0);
    __syncthreads();
    for (int kt = 0; kt < D; kt += 64) {
        stage(kt + 32, As1, Bs1);
        compute(As0, Bs0);
        __syncthreads();
        if (kt + 64 < D) stage(kt + 64, As0, Bs0);
        compute(As1, Bs1);
        __syncthreads();
    }
#pragma unroll
    for (int i = 0; i < 2; i++)
#pragma unroll
        for (int j = 0; j < 4; j++)
#pragma unroll
            for (int r = 0; r < 4; r++) {
                int m = m0 + wave * 32 + i * 16 + quad * 4 + r;
                int n = n0 + j * 16 + ln16;
                C[(size_t)m * D + n] = acc[i][j][r];
            }
}

// ---------------- residual + LayerNorm (wave-shuffle reduce) + x_imag copy
__global__ void ln_kernel(const float* __restrict__ xr, const float* __restrict__ o2,
                          const float* __restrict__ gamma, const float* __restrict__ beta,
                          float* __restrict__ outp, const float4* __restrict__ xi4,
                          float4* __restrict__ out1) {
    int l = blockIdx.x;
    int tid = threadIdx.x;
    int wave = tid >> 6;
    __shared__ float red[8];
    float hv[4];
    float s = 0.f;
#pragma unroll
    for (int i = 0; i < 4; i++) {
        int c = tid + i * 256;
        hv[i] = xr[(size_t)l * D + c] + o2[(size_t)l * D + c];
        s += hv[i];
    }
    out1[(size_t)l * (D / 4) + tid] = xi4[(size_t)l * (D / 4) + tid];
#pragma unroll
    for (int off = 1; off < 64; off <<= 1) s += __shfl_xor(s, off);
    if ((tid & 63) == 0) red[wave] = s;
    __syncthreads();
    float mu = (red[0] + red[1] + red[2] + red[3]) * (1.f / D);
    float v = 0.f;
#pragma unroll
    for (int i = 0; i < 4; i++) { float d = hv[i] - mu; v += d * d; }
#pragma unroll
    for (int off = 1; off < 64; off <<= 1) v += __shfl_xor(v, off);
    __syncthreads();
    if ((tid & 63) == 0) red[4 + wave] = v;
    __syncthreads();
    float rstd = rsqrtf((red[4] + red[5] + red[6] + red[7]) * (1.f / D) + 1e-5f);
#pragma unroll
    for (int i = 0; i < 4; i++) {
        int c = tid + i * 256;
        outp[(size_t)l * D + c] = (hv[i] - mu) * rstd * gamma[c] + beta[c];
    }
}

extern "C" void kernel_launch(void* const* d_in, const int* in_sizes, int n_in,
                              void* d_out, int out_size, void* d_ws, size_t ws_size,
                              hipStream_t stream) {
    const float* xr    = (const float*)d_in[0];
    const float* xi    = (const float*)d_in[1];
    const float* Wq    = (const float*)d_in[2];
    const float* Wk    = (const float*)d_in[3];
    const float* Wv    = (const float*)d_in[4];
    const float* Wqp   = (const float*)d_in[5];
    const float* bqp   = (const float*)d_in[6];
    const float* Wkp   = (const float*)d_in[7];
    const float* bkp   = (const float*)d_in[8];
    const float* Wo    = (const float*)d_in[9];
    const float* alpha = (const float*)d_in[10];
    const float* gamma = (const float*)d_in[11];
    const float* beta  = (const float*)d_in[12];

    const size_t LD = (size_t)L * D;
    const size_t MB = 1024 * 1024;

    // d_out A [0,8MB): xib(4, dead after qkv z=3) -> AOb(4) | Wot(2) | Wtq(2)
    //                  -> LN fp32 output (last)
    // d_out B [8,16MB): xrb(4) | Wtk(2) | Wtv(2) -> x_imag copy (last, via ln)
    char* A8 = (char*)d_out;
    char* B8 = A8 + LD * 4;
    ushort* xib = (ushort*)A8;
    ushort* AOb = (ushort*)A8;
    ushort* Wot = (ushort*)(A8 + 4 * MB);
    ushort* Wtq = (ushort*)(A8 + 6 * MB);
    ushort* xrb = (ushort*)B8;
    ushort* Wtk = (ushort*)(B8 + 4 * MB);
    ushort* Wtv = (ushort*)(B8 + 6 * MB);
    float* outf = (float*)d_out;

    // ws: Qe(6.29) | Ke(6.29) | Vte(4.19, transposed [h][d][L]) | Wqpkt(0.52)
    //     | Opart(8) | ml(0.26).  O2 fp32 overlays ws[0,8MB) (Qe/Ke dead after flash).
    ushort* Qe = (ushort*)d_ws;
    ushort* Ke = Qe + (size_t)NH * L * HDE;
    ushort* Ve = Ke + (size_t)NH * L * HDE;
    ushort* Wqpkt = Ve + (size_t)NH * L * HD;
    ushort* Opart = Wqpkt + (size_t)256 * D;            // NSPLIT x L*D bf16 = 8 MB
    float*  mlbuf = (float*)(Opart + (size_t)NSPLIT * LD);
    float*  O2 = (float*)d_ws;

    prep_kernel<<<8576, 256, 0, stream>>>(xr, xi, xrb, xib,
                                          Wq, Wk, Wv, Wo, Wqp, Wkp,
                                          Wtq, Wtk, Wtv, Wot, Wqpkt, Qe, Ke);

    qkv_gemm<<<dim3(8, 16, 4), 512, 0, stream>>>(xrb, xib, Wtq, Wtk, Wtv, Wqpkt,
                                                 Qe, Ke, Ve, alpha, bqp, bkp);

    flash_attn<<<512, 256, 0, stream>>>(Qe, Ke, Ve, Opart, mlbuf);

    comb_kernel<<<L, 256, 0, stream>>>(Opart, mlbuf, AOb);

    wo_gemm<<<dim3(16, 16), 256, 0, stream>>>(AOb, Wot, O2);

    ln_kernel<<<L, 256, 0, stream>>>(xr, O2, gamma, beta, outf,
                                     (const float4*)xi, (float4*)(B8));
}

// Round 10
// 172.379 us; speedup vs baseline: 1.1119x; 1.0263x over previous
//
#include <hip/hip_runtime.h>
#include <hip/hip_bf16.h>
#include <math.h>

#define L 2048
#define D 1024
#define NH 16
#define HD 64
#define P 128
#define HDE 96                              /* extended head dim 80, padded to 96 */
#define CONTENT_SCALE 0.125f                /* 1/sqrt(64) */
#define PHASE_SCALE   0.35355339059327373f  /* 1/sqrt(8) */
#define KLS 104                             /* Kl LDS stride */
#define VT2 136                             /* Vt LDS stride (128 cols + pad) */
#define NSPLIT 2

typedef short bf16x8 __attribute__((ext_vector_type(8)));
typedef float f32x4 __attribute__((ext_vector_type(4)));
typedef float f32x16 __attribute__((ext_vector_type(16)));

__device__ inline ushort f2b(float x) {
    __hip_bfloat16 b = __float2bfloat16(x);
    return *(ushort*)&b;
}
__device__ inline float b2f(ushort u) {
    unsigned v = (unsigned)u << 16;
    union { unsigned u; float f; } c; c.u = v; return c.f;
}

// hardware sincos: v_sin/v_cos take REVOLUTIONS; reduce with fract
__device__ inline void sincos_hw(float ang, float* sn, float* cs) {
    float rev = ang * 0.15915494309189535f;
    rev -= floorf(rev);
    *sn = __builtin_amdgcn_sinf(rev);
    *cs = __builtin_amdgcn_cosf(rev);
}

// async global->LDS, 16B per lane; LDS dest = wave-uniform base + lane*16
__device__ inline void gld_lds16(const void* g, void* l) {
    __builtin_amdgcn_global_load_lds(
        (const __attribute__((address_space(1))) unsigned int*)g,
        (__attribute__((address_space(3))) unsigned int*)l,
        16, 0, 0);
}

// ---------------- fused prep: [0,4096) cvt fp32->bf16, [4096,8448) transpose W,
// [8448,8576) zero Qe/Ke pad cols 80..95
__global__ void prep_kernel(const float* __restrict__ xr, const float* __restrict__ xi,
                            ushort* __restrict__ xrb, ushort* __restrict__ xib,
                            const float* __restrict__ W0, const float* __restrict__ W1,
                            const float* __restrict__ W2, const float* __restrict__ W3,
                            const float* __restrict__ W4, const float* __restrict__ W5,
                            ushort* __restrict__ T0, ushort* __restrict__ T1,
                            ushort* __restrict__ T2, ushort* __restrict__ T3,
                            ushort* __restrict__ Tp,
                            ushort* __restrict__ Qe, ushort* __restrict__ Ke) {
    __shared__ float tile[32][33];
    const int b = blockIdx.x;
    const int tid = threadIdx.x;
    if (b < 4096) {                          // cvt: 2 tensors x 2048 blocks
        const float4* src = (b >> 11) ? (const float4*)xi : (const float4*)xr;
        ushort4* dst = (b >> 11) ? (ushort4*)xib : (ushort4*)xrb;
        int i = ((b & 2047) << 8) + tid;
        float4 v = src[i];
        ushort4 o;
        o.x = f2b(v.x); o.y = f2b(v.y); o.z = f2b(v.z); o.w = f2b(v.w);
        dst[i] = o;
    } else if (b < 8448) {                   // transpose+convert weights
        int w = b - 4096;
        const float* W; ushort* T; int ncols, n0, k0;
        if (w < 4096) {
            int z = w >> 10, t = w & 1023;
            n0 = (t & 31) * 32; k0 = (t >> 5) * 32; ncols = D;
            W = (z == 0) ? W0 : ((z == 1) ? W1 : ((z == 2) ? W2 : W3));
            T = (z == 0) ? T0 : ((z == 1) ? T1 : ((z == 2) ? T2 : T3));
        } else {
            int w2 = w - 4096;
            int z = w2 >> 7, t = w2 & 127;
            n0 = (t & 3) * 32; k0 = (t >> 2) * 32; ncols = P;
            W = z ? W5 : W4;
            T = Tp + (size_t)z * P * D;
        }
        int tx = tid & 31, ty = tid >> 5;
#pragma unroll
        for (int i = 0; i < 4; i++)
            tile[ty + i * 8][tx] = W[(size_t)(k0 + ty + i * 8) * ncols + n0 + tx];
        __syncthreads();
#pragma unroll
        for (int i = 0; i < 4; i++)
            T[(size_t)(n0 + ty + i * 8) * D + k0 + tx] = f2b(tile[tx][ty + i * 8]);
    } else {                                 // zpad
        int i = (b - 8448) * 256 + tid;      // 0 .. NH*L-1
        size_t base = (size_t)i * HDE + 80;
        uint4 z4 = make_uint4(0, 0, 0, 0);
        *(uint4*)(Qe + base) = z4;
        *(uint4*)(Qe + base + 8) = z4;
        *(uint4*)(Ke + base) = z4;
        *(uint4*)(Ke + base + 8) = z4;
    }
}

// ---------------- fused QKV + phase MFMA GEMM. z=0..2: Q/K/V; z=3: phase (x<2)
// BK=64 static double-buffer: per phase, stage a 128x64 tile while computing the
// other (16 MFMA + 12 ds_read_b128 per wave per phase) -- barrier drains halve
// vs BK=32 and compute now covers the drain latency. Chunk-XOR swizzle
// (slot = chunk ^ (row&7), applied on the global SOURCE; gld_lds dest linear)
// keeps the 128B-stride ds_read_b128 pattern conflict-free.
__launch_bounds__(512)
__global__ void qkv_gemm(const ushort* __restrict__ Ab, const ushort* __restrict__ xib,
                         const ushort* __restrict__ Wtq, const ushort* __restrict__ Wtk,
                         const ushort* __restrict__ Wtv, const ushort* __restrict__ Wtp,
                         ushort* __restrict__ Qe, ushort* __restrict__ Ke,
                         ushort* __restrict__ Ve, const float* __restrict__ alpha,
                         const float* __restrict__ bqp, const float* __restrict__ bkp) {
    const int z = blockIdx.z;
    if (z == 3 && blockIdx.x >= 2) return;
    const ushort* At = (z == 3) ? xib : Ab;
    const ushort* Bt = (z == 0) ? Wtq : ((z == 1) ? Wtk : ((z == 2) ? Wtv : Wtp));
    __shared__ ushort As0[128 * 64], Bs0[128 * 64];   // 16 KB each
    __shared__ ushort As1[128 * 64], Bs1[128 * 64];   // 64 KB total
    const int tid = threadIdx.x;
    const int wave = tid >> 6, lane = tid & 63, quad = lane >> 4, ln16 = lane & 15;
    const int wm = wave >> 2, wn = wave & 3;
    const int m0 = blockIdx.y * 128, n0 = blockIdx.x * 128;
    f32x4 acc[4][2];
#pragma unroll
    for (int i = 0; i < 4; i++)
#pragma unroll
        for (int j = 0; j < 2; j++) acc[i][j] = (f32x4){0.f, 0.f, 0.f, 0.f};

    // staging: LDS slot s = row*8 + cslot holds logical chunk cslot ^ (row&7).
    // thread handles slots tid (rows 0..63) and tid+512 (rows 64..127).
    const int sr1 = tid >> 3;
    const int scl = (tid & 7) ^ (sr1 & 7);   // same value for both slots (row&7 preserved)

    auto stage = [&](int kt, ushort* Asb, ushort* Bsb) {
        gld_lds16(At + (size_t)(m0 + sr1) * D + kt + scl * 8, &Asb[tid * 8]);
        gld_lds16(Bt + (size_t)(n0 + sr1) * D + kt + scl * 8, &Bsb[tid * 8]);
        gld_lds16(At + (size_t)(m0 + 64 + sr1) * D + kt + scl * 8, &Asb[(tid + 512) * 8]);
        gld_lds16(Bt + (size_t)(n0 + 64 + sr1) * D + kt + scl * 8, &Bsb[(tid + 512) * 8]);
    };
    auto compute = [&](const ushort* Asb, const ushort* Bsb) {
#pragma unroll
        for (int kk = 0; kk < 2; kk++) {     // kk order preserves kt,kt+32 acc order
            bf16x8 af[4], bfr[2];
#pragma unroll
            for (int t = 0; t < 4; t++) {
                int row = wm * 64 + t * 16 + ln16;
                int slot = (kk * 4 + quad) ^ (row & 7);
                af[t] = *(const bf16x8*)(&Asb[(row * 8 + slot) * 8]);
            }
#pragma unroll
            for (int j = 0; j < 2; j++) {
                int row = wn * 32 + j * 16 + ln16;
                int slot = (kk * 4 + quad) ^ (row & 7);
                bfr[j] = *(const bf16x8*)(&Bsb[(row * 8 + slot) * 8]);
            }
#pragma unroll
            for (int i = 0; i < 4; i++)
#pragma unroll
                for (int j = 0; j < 2; j++)
                    acc[i][j] = __builtin_amdgcn_mfma_f32_16x16x32_bf16(af[i], bfr[j], acc[i][j], 0, 0, 0);
        }
    };

    stage(0, As0, Bs0);
    __syncthreads();
    for (int kt = 0; kt < D; kt += 128) {
        stage(kt + 64, As1, Bs1);            // write b1 (readers done at prev barrier)
        compute(As0, Bs0);                   // read b0 (no alias with b1 writes)
        __syncthreads();
        if (kt + 128 < D) stage(kt + 128, As0, Bs0);
        compute(As1, Bs1);
        __syncthreads();
    }

    if (z == 2) {                            // V epilogue -> transposed Vte[h][d][L]
        int hn = (n0 >> 6) + (wn >> 1);
#pragma unroll
        for (int i = 0; i < 4; i++)
#pragma unroll
            for (int j = 0; j < 2; j++) {
                int d = (wn & 1) * 32 + j * 16 + ln16;
                int m = m0 + wm * 64 + i * 16 + quad * 4;
                ushort4 pk;
                pk.x = f2b(acc[i][j][0]); pk.y = f2b(acc[i][j][1]);
                pk.z = f2b(acc[i][j][2]); pk.w = f2b(acc[i][j][3]);
                *(ushort4*)(Ve + ((size_t)hn * HD + d) * L + m) = pk;
            }
    } else if (z < 2) {                      // Q/K epilogue, row-major [h][m][c]
        int hn = (n0 >> 6) + (wn >> 1);
        float s = (z == 0) ? (1.f - 1.f / (1.f + __expf(-alpha[hn]))) * CONTENT_SCALE : 1.f;
        ushort* dst = (z == 0) ? Qe : Ke;
#pragma unroll
        for (int i = 0; i < 4; i++)
#pragma unroll
            for (int j = 0; j < 2; j++) {
                int dcol = (wn & 1) * 32 + j * 16 + ln16;
#pragma unroll
                for (int r = 0; r < 4; r++) {
                    int m = m0 + wm * 64 + i * 16 + quad * 4 + r;
                    dst[((size_t)hn * L + m) * HDE + dcol] = f2b(acc[i][j][r] * s);
                }
            }
    } else {                                 // phase epilogue -> Qe/Ke cols 64..79
#pragma unroll
        for (int j = 0; j < 2; j++) {
            int cg = n0 + wn * 32 + j * 16 + ln16;   // 0..255
            int isQ = cg < P;
            int c = cg & (P - 1);
            int hh = c >> 3, jj = c & 7;
            float b = isQ ? bqp[c] : bkp[c];
            float sc = isQ ? (1.f / (1.f + __expf(-alpha[hh]))) * PHASE_SCALE : 1.f;
            float invf = __expf(-((float)(c & ~1) / 128.f) * 9.210340371976184f);
            ushort* dst = isQ ? Qe : Ke;
#pragma unroll
            for (int i = 0; i < 4; i++)
#pragma unroll
                for (int r = 0; r < 4; r++) {
                    int m = m0 + wm * 64 + i * 16 + quad * 4 + r;
                    float qt = acc[i][j][r] + b + (float)m * invf;
                    float sn, cs;
                    sincos_hw(qt, &sn, &cs);
                    size_t base = ((size_t)hh * L + m) * HDE;
                    dst[base + 64 + jj] = f2b(sc * cs);
                    dst[base + 72 + jj] = f2b(sc * sn);
                }
        }
    }
}

// ---------------- flash attention: 32x32x16 MFMA, swapped QK^T (P lane-local),
// KVBLK=128, l-sum via MFMA with ones-B, NSPLIT=2 CU-pairing.
__launch_bounds__(256, 2)
__global__ void flash_attn(const ushort* __restrict__ Qe, const ushort* __restrict__ Ke,
                           const ushort* __restrict__ Vte,
                           ushort* __restrict__ Opart, float* __restrict__ ml) {
    const int b = blockIdx.x;
    const int xcd = b & 7;
    const int r = b >> 3;                    // 0..63 per XCD
    const int idx = r & 31, sub = r >> 5;    // r and r+32 land on the same CU
    const int hbit = idx >> 4, c0i = idx & 15;
    const int c = sub ? 15 - c0i : c0i;      // complementary chunk sizes pair up
    const int z = sub;
    const int h = xcd * 2 + hbit;
    const int tid = threadIdx.x;
    const int wave = tid >> 6, lane = tid & 63;
    const int ln32 = lane & 31, hf = lane >> 5;

    const int nT = c + 1;                    // 64-key tiles [z*(c+1), (z+1)*(c+1))
    const int s0 = z * nT;
    const int nR = (nT + 1) >> 1;            // 128-key rounds
    const int qw = c * 128 + wave * 32;      // wave's 32-row q strip

    __shared__ ushort Kl[128 * KLS];         // 26.6 KB
    __shared__ ushort Vt[64 * VT2];          // 17.4 KB

    const ushort* Kh = Ke + (size_t)h * L * HDE;
    const ushort* Vh = Vte + (size_t)h * HD * L;
    const ushort* Qh = Qe + (size_t)h * L * HDE;
    ushort* Op = Opart + (size_t)z * L * D;
    float* mlp = ml + (size_t)z * NH * L + (size_t)h * L;

    bf16x8 onesv;
#pragma unroll
    for (int i = 0; i < 8; i++) onesv[i] = (short)0x3F80;   // bf16 1.0

    // Q B-frags (col=q=ln32, contract c = cc*16 + hf*8 + j), loaded once
    bf16x8 qa[6];
#pragma unroll
    for (int cc = 0; cc < 6; cc++)
        qa[cc] = *(const bf16x8*)(Qh + (size_t)(qw + ln32) * HDE + cc * 16 + hf * 8);

    f32x16 o[2], olv;
#pragma unroll
    for (int i = 0; i < 16; i++) { o[0][i] = 0.f; o[1][i] = 0.f; olv[i] = 0.f; }

    // staging geometry (constant per thread)
    int rowk[6], colk[6];
#pragma unroll
    for (int ii = 0; ii < 6; ii++) {
        int ix = ii * 256 + tid;             // 1536 = 128 rows x 12 16B-chunks
        rowk[ii] = ix / 12; colk[ii] = ix - rowk[ii] * 12;
    }
    int dv[4], cv[4];
#pragma unroll
    for (int ii = 0; ii < 4; ii++) {
        int ix = ii * 256 + tid;             // 1024 = 64 d-rows x 16 16B-chunks
        dv[ii] = ix >> 4; cv[ii] = ix & 15;
    }

    bf16x8 kreg[6], vreg[4];
    {
        int kk = s0 * 64;
#pragma unroll
        for (int ii = 0; ii < 6; ii++)
            kreg[ii] = *(const bf16x8*)(Kh + (size_t)(kk + rowk[ii]) * HDE + colk[ii] * 8);
#pragma unroll
        for (int ii = 0; ii < 4; ii++)
            vreg[ii] = *(const bf16x8*)(Vh + (size_t)dv[ii] * L + kk + cv[ii] * 8);
    }

    for (int rr = 0; rr < nR; rr++) {
        const int tk0 = (s0 + rr * 2) * 64;
        __syncthreads();
#pragma unroll
        for (int ii = 0; ii < 6; ii++)
            *(bf16x8*)(&Kl[rowk[ii] * KLS + colk[ii] * 8]) = kreg[ii];
#pragma unroll
        for (int ii = 0; ii < 4; ii++)
            *(bf16x8*)(&Vt[dv[ii] * VT2 + cv[ii] * 8]) = vreg[ii];
        __syncthreads();

        if (rr + 1 < nR) {                   // prefetch next 128-key round
            int kk = tk0 + 128;
#pragma unroll
            for (int ii = 0; ii < 6; ii++)
                kreg[ii] = *(const bf16x8*)(Kh + (size_t)(kk + rowk[ii]) * HDE + colk[ii] * 8);
#pragma unroll
            for (int ii = 0; ii < 4; ii++)
                vreg[ii] = *(const bf16x8*)(Vh + (size_t)dv[ii] * L + kk + cv[ii] * 8);
        }

#pragma unroll
        for (int hb = 0; hb < 2; hb++) {
            const int tt = rr * 2 + hb;
            const int k0 = tk0 + hb * 64;
            if (tt < nT && k0 < qw + 32) {   // wave-uniform skip
                // QK^T swapped: s2[kb] = K_tile(32k x 96c) . Q^T -> D[k][q], col=q=ln32
                f32x16 s2[2];
#pragma unroll
                for (int i = 0; i < 16; i++) { s2[0][i] = 0.f; s2[1][i] = 0.f; }
                __builtin_amdgcn_s_setprio(1);
#pragma unroll
                for (int kb = 0; kb < 2; kb++)
#pragma unroll
                    for (int cc = 0; cc < 6; cc++) {
                        bf16x8 kf = *(const bf16x8*)(&Kl[(hb * 64 + kb * 32 + ln32) * KLS + cc * 16 + hf * 8]);
                        s2[kb] = __builtin_amdgcn_mfma_f32_32x32x16_bf16(kf, qa[cc], s2[kb], 0, 0, 0);
                    }
                __builtin_amdgcn_s_setprio(0);

                if (k0 + 63 > qw) {          // diagonal region: causal mask
#pragma unroll
                    for (int kb = 0; kb < 2; kb++)
#pragma unroll
                        for (int rg = 0; rg < 16; rg++) {
                            int key = k0 + kb * 32 + (rg & 3) + 8 * (rg >> 2) + 4 * hf;
                            if (key > qw + ln32) s2[kb][rg] = -1e30f;
                        }
                }

                // P = exp(s) in place (scores bounded; no max, no rescale)
#pragma unroll
                for (int kb = 0; kb < 2; kb++)
#pragma unroll
                    for (int rg = 0; rg < 16; rg++)
                        s2[kb][rg] = __expf(s2[kb][rg]);

                // pack P->bf16 pairs (per t-quad: X = regs 4t,4t+1; Y = 4t+2,4t+3)
                unsigned Xp[2][4], Yp[2][4];
#pragma unroll
                for (int kb = 0; kb < 2; kb++)
#pragma unroll
                    for (int tq = 0; tq < 4; tq++) {
                        asm("v_cvt_pk_bf16_f32 %0, %1, %2"
                            : "=v"(Xp[kb][tq]) : "v"(s2[kb][4 * tq + 0]), "v"(s2[kb][4 * tq + 1]));
                        asm("v_cvt_pk_bf16_f32 %0, %1, %2"
                            : "=v"(Yp[kb][tq]) : "v"(s2[kb][4 * tq + 2]), "v"(s2[kb][4 * tq + 3]));
                    }

                // build PV A-frags via half-exchange: pa[m] covers k = m*16 + hf*8 + j
                bf16x8 pa[4];
#pragma unroll
                for (int m = 0; m < 4; m++) {
                    int kb = m >> 1, te = 2 * (m & 1), to = te + 1;
                    unsigned x0 = Xp[kb][te], x1 = Xp[kb][to];
                    unsigned y0 = Yp[kb][te], y1 = Yp[kb][to];
                    asm("v_permlane32_swap_b32 %0, %1" : "+v"(x0), "+v"(x1));
                    asm("v_permlane32_swap_b32 %0, %1" : "+v"(y0), "+v"(y1));
                    union { unsigned u[4]; bf16x8 v; } pb;
                    pb.u[0] = x0; pb.u[1] = y0; pb.u[2] = x1; pb.u[3] = y1;
                    pa[m] = pb.v;
                }

                // PV: o[db] (rows q, cols d = db*32+ln32); l-sum via ones-B MFMA
                __builtin_amdgcn_s_setprio(1);
#pragma unroll
                for (int m = 0; m < 4; m++) {
#pragma unroll
                    for (int db = 0; db < 2; db++) {
                        bf16x8 vf = *(const bf16x8*)(&Vt[(db * 32 + ln32) * VT2 + hb * 64 + m * 16 + hf * 8]);
                        o[db] = __builtin_amdgcn_mfma_f32_32x32x16_bf16(pa[m], vf, o[db], 0, 0, 0);
                    }
                    olv = __builtin_amdgcn_mfma_f32_32x32x16_bf16(pa[m], onesv, olv, 0, 0, 0);
                }
                __builtin_amdgcn_s_setprio(0);
            }
        }
    }

    // l write: olv row q = (rg&3)+8*(rg>>2)+4*hf, all cols equal -> col 0 writes
    if (ln32 == 0) {
#pragma unroll
        for (int rg = 0; rg < 16; rg++) {
            int q = qw + (rg & 3) + 8 * (rg >> 2) + 4 * hf;
            mlp[q] = olv[rg];
        }
    }
    // write partial O: lane col d = db*32+ln32, row q = (rg&3)+8*(rg>>2)+4*hf
#pragma unroll
    for (int db = 0; db < 2; db++)
#pragma unroll
        for (int rg = 0; rg < 16; rg++) {
            int q = qw + (rg & 3) + 8 * (rg >> 2) + 4 * hf;
            Op[(size_t)q * D + h * HD + db * 32 + ln32] = f2b(o[db][rg]);
        }
}

// ---------------- combine the split partials -> normalized AOb (reads Opart ONCE)
__global__ void comb_kernel(const ushort* __restrict__ Opart, const float* __restrict__ ml,
                            ushort* __restrict__ AOb) {
    int q = blockIdx.x;
    int t = threadIdx.x;                     // dims t*4..t*4+3, h = t>>4
    int h = t >> 4;
    float lsum = 0.f;
#pragma unroll
    for (int zz = 0; zz < NSPLIT; zz++)
        lsum += ml[(size_t)zz * NH * L + (size_t)h * L + q];
    float inv = 1.f / lsum;
    size_t idx = (size_t)q * D + t * 4;
    float ox = 0.f, oy = 0.f, oz = 0.f, ow = 0.f;
#pragma unroll
    for (int zz = 0; zz < NSPLIT; zz++) {
        ushort4 a = *(const ushort4*)(Opart + (size_t)zz * L * D + idx);
        ox += b2f(a.x); oy += b2f(a.y); oz += b2f(a.z); ow += b2f(a.w);
    }
    ushort4 o;
    o.x = f2b(ox * inv); o.y = f2b(oy * inv);
    o.z = f2b(oz * inv); o.w = f2b(ow * inv);
    *(ushort4*)(AOb + idx) = o;
}

// ---------------- Wo MFMA GEMM: O2 fp32 = AOb @ Wot.
// 128x64 tiles, grid 16x16 = 256 blocks (1/CU). Static dbuf + XOR swizzle.
__launch_bounds__(256)
__global__ void wo_gemm(const ushort* __restrict__ Ab, const ushort* __restrict__ Bt,
                        float* __restrict__ C) {
    __shared__ ushort As0[128 * 32], Bs0[64 * 32];
    __shared__ ushort As1[128 * 32], Bs1[64 * 32];
    const int tid = threadIdx.x;
    const int wave = tid >> 6, lane = tid & 63, quad = lane >> 4, ln16 = lane & 15;
    const int m0 = blockIdx.y * 128, n0 = blockIdx.x * 64;
    const int swr = (ln16 >> 1) & 3;         // read-side swizzle (row>>1)&3
    f32x4 acc[2][4];
#pragma unroll
    for (int i = 0; i < 2; i++)
#pragma unroll
        for (int j = 0; j < 4; j++) acc[i][j] = (f32x4){0.f, 0.f, 0.f, 0.f};

    auto stage = [&](int kt, ushort* Asb, ushort* Bsb) {
#pragma unroll
        for (int i = 0; i < 2; i++) {        // A: 128x32 = 8KB = 2 issues
            int idx = i * 256 + tid;
            int r2 = idx >> 2, cc = idx & 3;
            int cc2 = cc ^ ((r2 >> 1) & 3);
            gld_lds16(Ab + (size_t)(m0 + r2) * D + kt + cc2 * 8, &Asb[idx * 8]);
        }
        {                                    // B: 64x32 = 4KB = 1 issue
            int r2 = tid >> 2, cc = tid & 3;
            int cc2 = cc ^ ((r2 >> 1) & 3);
            gld_lds16(Bt + (size_t)(n0 + r2) * D + kt + cc2 * 8, &Bsb[tid * 8]);
        }
    };
    auto compute = [&](const ushort* Asb, const ushort* Bsb) {
        bf16x8 af[2], bfr[4];
#pragma unroll
        for (int i = 0; i < 2; i++)
            af[i] = *(const bf16x8*)(&Asb[(wave * 32 + i * 16 + ln16) * 32 + (quad ^ swr) * 8]);
#pragma unroll
        for (int j = 0; j < 4; j++)
            bfr[j] = *(const bf16x8*)(&Bsb[(j * 16 + ln16) * 32 + (quad ^ swr) * 8]);
#pragma unroll
        for (int i = 0; i < 2; i++)
#pragma unroll
            for (int j = 0; j < 4; j++)
                acc[i][j] = __builtin_amdgcn_mfma_f32_16x16x32_bf16(af[i], bfr[j], acc[i][j], 0, 0, 0);
    };

    stage(0, As0, Bs0);
    __syncthreads();
    for (int kt = 0; kt < D; kt += 64) {
        stage(kt + 32, As1, Bs1);
        compute(As0, Bs0);
        __syncthreads();
        if (kt + 64 < D) stage(kt + 64, As0, Bs0);
        compute(As1, Bs1);
        __syncthreads();
    }
#pragma unroll
    for (int i = 0; i < 2; i++)
#pragma unroll
        for (int j = 0; j < 4; j++)
#pragma unroll
            for (int r = 0; r < 4; r++) {
                int m = m0 + wave * 32 + i * 16 + quad * 4 + r;
                int n = n0 + j * 16 + ln16;
                C[(size_t)m * D + n] = acc[i][j][r];
            }
}

// ---------------- residual + LayerNorm (wave-shuffle reduce) + x_imag copy
__global__ void ln_kernel(const float* __restrict__ xr, const float* __restrict__ o2,
                          const float* __restrict__ gamma, const float* __restrict__ beta,
                          float* __restrict__ outp, const float4* __restrict__ xi4,
                          float4* __restrict__ out1) {
    int l = blockIdx.x;
    int tid = threadIdx.x;
    int wave = tid >> 6;
    __shared__ float red[8];
    float hv[4];
    float s = 0.f;
#pragma unroll
    for (int i = 0; i < 4; i++) {
        int c = tid + i * 256;
        hv[i] = xr[(size_t)l * D + c] + o2[(size_t)l * D + c];
        s += hv[i];
    }
    out1[(size_t)l * (D / 4) + tid] = xi4[(size_t)l * (D / 4) + tid];
#pragma unroll
    for (int off = 1; off < 64; off <<= 1) s += __shfl_xor(s, off);
    if ((tid & 63) == 0) red[wave] = s;
    __syncthreads();
    float mu = (red[0] + red[1] + red[2] + red[3]) * (1.f / D);
    float v = 0.f;
#pragma unroll
    for (int i = 0; i < 4; i++) { float d = hv[i] - mu; v += d * d; }
#pragma unroll
    for (int off = 1; off < 64; off <<= 1) v += __shfl_xor(v, off);
    __syncthreads();
    if ((tid & 63) == 0) red[4 + wave] = v;
    __syncthreads();
    float rstd = rsqrtf((red[4] + red[5] + red[6] + red[7]) * (1.f / D) + 1e-5f);
#pragma unroll
    for (int i = 0; i < 4; i++) {
        int c = tid + i * 256;
        outp[(size_t)l * D + c] = (hv[i] - mu) * rstd * gamma[c] + beta[c];
    }
}

extern "C" void kernel_launch(void* const* d_in, const int* in_sizes, int n_in,
                              void* d_out, int out_size, void* d_ws, size_t ws_size,
                              hipStream_t stream) {
    const float* xr    = (const float*)d_in[0];
    const float* xi    = (const float*)d_in[1];
    const float* Wq    = (const float*)d_in[2];
    const float* Wk    = (const float*)d_in[3];
    const float* Wv    = (const float*)d_in[4];
    const float* Wqp   = (const float*)d_in[5];
    const float* bqp   = (const float*)d_in[6];
    const float* Wkp   = (const float*)d_in[7];
    const float* bkp   = (const float*)d_in[8];
    const float* Wo    = (const float*)d_in[9];
    const float* alpha = (const float*)d_in[10];
    const float* gamma = (const float*)d_in[11];
    const float* beta  = (const float*)d_in[12];

    const size_t LD = (size_t)L * D;
    const size_t MB = 1024 * 1024;

    // d_out A [0,8MB): xib(4, dead after qkv z=3) -> AOb(4) | Wot(2) | Wtq(2)
    //                  -> LN fp32 output (last)
    // d_out B [8,16MB): xrb(4) | Wtk(2) | Wtv(2) -> x_imag copy (last, via ln)
    char* A8 = (char*)d_out;
    char* B8 = A8 + LD * 4;
    ushort* xib = (ushort*)A8;
    ushort* AOb = (ushort*)A8;
    ushort* Wot = (ushort*)(A8 + 4 * MB);
    ushort* Wtq = (ushort*)(A8 + 6 * MB);
    ushort* xrb = (ushort*)B8;
    ushort* Wtk = (ushort*)(B8 + 4 * MB);
    ushort* Wtv = (ushort*)(B8 + 6 * MB);
    float* outf = (float*)d_out;

    // ws: Qe(6.29) | Ke(6.29) | Vte(4.19, transposed [h][d][L]) | Wqpkt(0.52)
    //     | Opart(8) | ml(0.26).  O2 fp32 overlays ws[0,8MB) (Qe/Ke dead after flash).
    ushort* Qe = (ushort*)d_ws;
    ushort* Ke = Qe + (size_t)NH * L * HDE;
    ushort* Ve = Ke + (size_t)NH * L * HDE;
    ushort* Wqpkt = Ve + (size_t)NH * L * HD;
    ushort* Opart = Wqpkt + (size_t)256 * D;            // NSPLIT x L*D bf16 = 8 MB
    float*  mlbuf = (float*)(Opart + (size_t)NSPLIT * LD);
    float*  O2 = (float*)d_ws;

    prep_kernel<<<8576, 256, 0, stream>>>(xr, xi, xrb, xib,
                                          Wq, Wk, Wv, Wo, Wqp, Wkp,
                                          Wtq, Wtk, Wtv, Wot, Wqpkt, Qe, Ke);

    qkv_gemm<<<dim3(8, 16, 4), 512, 0, stream>>>(xrb, xib, Wtq, Wtk, Wtv, Wqpkt,
                                                 Qe, Ke, Ve, alpha, bqp, bkp);

    flash_attn<<<512, 256, 0, stream>>>(Qe, Ke, Ve, Opart, mlbuf);

    comb_kernel<<<L, 256, 0, stream>>>(Opart, mlbuf, AOb);

    wo_gemm<<<dim3(16, 16), 256, 0, stream>>>(AOb, Wot, O2);

    ln_kernel<<<L, 256, 0, stream>>>(xr, O2, gamma, beta, outf,
                                     (const float4*)xi, (float4*)(B8));
}